// Round 1
// baseline (1512.445 us; speedup 1.0000x reference)
//
#include <hip/hip_runtime.h>
#include <hip/hip_bf16.h>
#include <math.h>

#define N_USERS 8000
#define N_ENTITIES 32000
#define EMB 64
#define N_GROUPS 4
#define N_EDGES 200000
#define INV_TAU 2.0f

// ---------------------------------------------------------------------------
// Edge scatter: one wave per edge, lane = embedding dim.
//   udst[ui[e]] += esrc[ei[e]]   (always)
//   edst[ei[e]] += usrc[ui[e]]   (if do_e)
// ---------------------------------------------------------------------------
__global__ __launch_bounds__(256) void edge_scatter(
    const int* __restrict__ ui, const int* __restrict__ ei,
    const float* __restrict__ usrc, const float* __restrict__ esrc,
    float* __restrict__ udst, float* __restrict__ edst, int do_e)
{
    int e = blockIdx.x * 4 + (threadIdx.x >> 6);
    if (e >= N_EDGES) return;
    int lane = threadIdx.x & 63;
    int u = ui[e];
    int v = ei[e];
    atomicAdd(&udst[u * EMB + lane], esrc[v * EMB + lane]);
    if (do_e) atomicAdd(&edst[v * EMB + lane], usrc[u * EMB + lane]);
}

// ---------------------------------------------------------------------------
// Row L2-normalize in place; mode 1: acc = normalized, mode 2: acc += normalized
// ---------------------------------------------------------------------------
__global__ __launch_bounds__(256) void norm_rows(
    float* __restrict__ buf, float* __restrict__ acc, int rows, int mode)
{
    int row = blockIdx.x * 4 + (threadIdx.x >> 6);
    if (row >= rows) return;
    int lane = threadIdx.x & 63;
    float v = buf[row * EMB + lane];
    float ss = v * v;
    #pragma unroll
    for (int off = 1; off < 64; off <<= 1) ss += __shfl_xor(ss, off);
    float o = v / fmaxf(sqrtf(ss), 1e-12f);
    buf[row * EMB + lane] = o;
    if (mode == 1)      acc[row * EMB + lane] = o;
    else if (mode == 2) acc[row * EMB + lane] += o;
}

// ---------------------------------------------------------------------------
// Attention combine: scores -> softmax over 4 groups -> weighted sum + user_emb
// ---------------------------------------------------------------------------
__global__ __launch_bounds__(256) void combine_att(
    const float* __restrict__ acc, const float* __restrict__ uie,
    const float* __restrict__ uemb, float* __restrict__ out)
{
    int u = blockIdx.x * 4 + (threadIdx.x >> 6);
    if (u >= N_USERS) return;
    int lane = threadIdx.x & 63;
    float ue = uie[u * EMB + lane];
    float s[N_GROUPS];
    #pragma unroll
    for (int g = 0; g < N_GROUPS; ++g) {
        float p = acc[(size_t)g * N_USERS * EMB + u * EMB + lane] * ue;
        #pragma unroll
        for (int off = 1; off < 64; off <<= 1) p += __shfl_xor(p, off);
        s[g] = p;
    }
    float m = fmaxf(fmaxf(s[0], s[1]), fmaxf(s[2], s[3]));
    float att[N_GROUPS], tot = 0.f;
    #pragma unroll
    for (int g = 0; g < N_GROUPS; ++g) { att[g] = __expf(s[g] - m); tot += att[g]; }
    float inv = 1.0f / tot;
    float o = uemb[u * EMB + lane];
    #pragma unroll
    for (int g = 0; g < N_GROUPS; ++g)
        o += att[g] * inv * acc[(size_t)g * N_USERS * EMB + u * EMB + lane];
    out[u * EMB + lane] = o;
}

// ---------------------------------------------------------------------------
// proj(z) = elu(z@W1+b1)@W2 + b2, then L2-normalize rows. blockIdx.y picks
// (src1->dst1) or (src2->dst2). One wave per row, weights staged in LDS.
// ---------------------------------------------------------------------------
__global__ __launch_bounds__(256) void proj_norm(
    const float* __restrict__ src1, const float* __restrict__ src2,
    const float* __restrict__ W1, const float* __restrict__ b1,
    const float* __restrict__ W2, const float* __restrict__ b2,
    float* __restrict__ dst1, float* __restrict__ dst2)
{
    __shared__ float W1s[EMB * EMB];
    __shared__ float W2s[EMB * EMB];
    __shared__ float zs[4][EMB];
    __shared__ float hs[4][EMB];
    const float* src = blockIdx.y ? src2 : src1;
    float* dst = blockIdx.y ? dst2 : dst1;
    int t = threadIdx.x;
    for (int i = t; i < EMB * EMB; i += 256) { W1s[i] = W1[i]; W2s[i] = W2[i]; }
    int w = t >> 6, lane = t & 63;
    int row = blockIdx.x * 4 + w;
    float z = src[row * EMB + lane];
    zs[w][lane] = z;
    __syncthreads();
    float h = b1[lane];
    #pragma unroll
    for (int k = 0; k < EMB; ++k) h = fmaf(zs[w][k], W1s[k * EMB + lane], h);
    h = h > 0.f ? h : expm1f(h);
    hs[w][lane] = h;
    __syncthreads();
    float y = b2[lane];
    #pragma unroll
    for (int k = 0; k < EMB; ++k) y = fmaf(hs[w][k], W2s[k * EMB + lane], y);
    float ss = y * y;
    #pragma unroll
    for (int off = 1; off < 64; off <<= 1) ss += __shfl_xor(ss, off);
    dst[row * EMB + lane] = y / fmaxf(sqrtf(ss), 1e-12f);
}

// ---------------------------------------------------------------------------
// Fused "GEMM + row logsumexp" without materializing the 8000x8000 matrix.
// Block: 192 threads; owns IB=8 rows of A; loops over all B rows in chunks
// of JB=192 staged in LDS (one column j per thread, cached in registers).
// sumexp[i] += sum_j exp(2*dot(A_i,B_j)); optionally records diag logits.
// ---------------------------------------------------------------------------
#define JB 192
#define IB 8
__global__ __launch_bounds__(192) void lse_pass(
    const float* __restrict__ A, const float* __restrict__ B,
    float* __restrict__ sumexp, float* __restrict__ diag, int writeDiag)
{
    __shared__ float As[IB][EMB];
    __shared__ float Bs[JB][68];      // pad to 68 floats (16B aligned, bank-spread)
    int t = threadIdx.x;
    int i0 = blockIdx.x * IB;
    for (int i = t; i < IB * EMB; i += 192) As[i >> 6][i & 63] = A[i0 * EMB + i];
    float partial[IB];
    #pragma unroll
    for (int r = 0; r < IB; ++r) partial[r] = 0.f;

    for (int chunk = 0; chunk < N_USERS; chunk += JB) {
        __syncthreads();
        // stage JB rows of B: 192*64 floats = 3072 float4, 16 per thread
        #pragma unroll
        for (int it = 0; it < 16; ++it) {
            int idx4 = it * 192 + t;
            int row = idx4 >> 4;
            int col = (idx4 & 15) << 2;
            int j = chunk + row;
            float4 val = make_float4(0.f, 0.f, 0.f, 0.f);
            if (j < N_USERS) val = ((const float4*)B)[j * 16 + (idx4 & 15)];
            *(float4*)&Bs[row][col] = val;
        }
        __syncthreads();
        int j = chunk + t;
        if (j < N_USERS) {
            float4 breg[16];
            #pragma unroll
            for (int k = 0; k < 16; ++k) breg[k] = *(const float4*)&Bs[t][k << 2];
            #pragma unroll
            for (int r = 0; r < IB; ++r) {
                float dot = 0.f;
                #pragma unroll
                for (int k = 0; k < 16; ++k) {
                    float4 a = *(const float4*)&As[r][k << 2];
                    float4 b = breg[k];
                    dot = fmaf(a.x, b.x, dot); dot = fmaf(a.y, b.y, dot);
                    dot = fmaf(a.z, b.z, dot); dot = fmaf(a.w, b.w, dot);
                }
                float logit = dot * INV_TAU;
                partial[r] += __expf(logit);
                if (writeDiag && j == i0 + r) diag[j] = logit;
            }
        }
    }
    #pragma unroll
    for (int r = 0; r < IB; ++r) {
        float v = partial[r];
        #pragma unroll
        for (int off = 1; off < 64; off <<= 1) v += __shfl_xor(v, off);
        if ((t & 63) == 0) atomicAdd(&sumexp[i0 + r], v);
    }
}

// ---------------------------------------------------------------------------
// loss = mean_i( 0.5*(log(se_row)+log(se_col)) - diag )
// ---------------------------------------------------------------------------
__global__ __launch_bounds__(256) void loss_kernel(
    const float* __restrict__ se_row, const float* __restrict__ se_col,
    const float* __restrict__ diag, float* __restrict__ out)
{
    __shared__ float red[256];
    int t = threadIdx.x;
    float s = 0.f;
    for (int i = t; i < N_USERS; i += 256)
        s += 0.5f * (logf(se_row[i]) + logf(se_col[i])) - diag[i];
    red[t] = s;
    __syncthreads();
    for (int w = 128; w > 0; w >>= 1) {
        if (t < w) red[t] += red[t + w];
        __syncthreads();
    }
    if (t == 0) out[0] = red[0] / (float)N_USERS;
}

extern "C" void kernel_launch(void* const* d_in, const int* in_sizes, int n_in,
                              void* d_out, int out_size, void* d_ws, size_t ws_size,
                              hipStream_t stream)
{
    const float* user_emb   = (const float*)d_in[0];
    const float* user_ui    = (const float*)d_in[1];
    const float* entity_emb = (const float*)d_in[2];
    const float* W1 = (const float*)d_in[3];
    const float* b1 = (const float*)d_in[4];
    const float* W2 = (const float*)d_in[5];
    const float* b2 = (const float*)d_in[6];
    const int* ui_index = (const int*)d_in[7];
    const int* ei_index = (const int*)d_in[8];

    float* ws     = (float*)d_ws;
    float* acc    = ws;                       // 4 * 512000
    float* ubuf   = acc + 4 * 512000;         // 512000
    float* ebuf   = ubuf + 512000;            // 2048000
    float* p1     = ebuf + 2048000;           // 512000
    float* p2     = p1 + 512000;              // 512000
    float* se_row = p2 + 512000;              // 8000
    float* se_col = se_row + 8000;            // 8000
    float* diag   = se_col + 8000;            // 8000

    float* out_user = (float*)d_out;          // 512000
    float* out_loss = out_user + 512000;      // 1

    dim3 b256(256);
    for (int g = 0; g < N_GROUPS; ++g) {
        const int* ui = ui_index + (size_t)g * N_EDGES;
        const int* ei = ei_index + (size_t)g * N_EDGES;
        float* acc_g = acc + (size_t)g * N_USERS * EMB;
        // hop 0: u_agg from entity_emb, e_int from user_emb
        hipMemsetAsync(ubuf, 0, (size_t)N_USERS * EMB * 4, stream);
        hipMemsetAsync(ebuf, 0, (size_t)N_ENTITIES * EMB * 4, stream);
        edge_scatter<<<(N_EDGES + 3) / 4, b256, 0, stream>>>(
            ui, ei, user_emb, entity_emb, ubuf, ebuf, 1);
        norm_rows<<<N_USERS / 4, b256, 0, stream>>>(ubuf, acc_g, N_USERS, 1);
        norm_rows<<<N_ENTITIES / 4, b256, 0, stream>>>(ebuf, nullptr, N_ENTITIES, 0);
        // hop 1: u_agg from normalized e_int (entity side never consumed again)
        hipMemsetAsync(ubuf, 0, (size_t)N_USERS * EMB * 4, stream);
        edge_scatter<<<(N_EDGES + 3) / 4, b256, 0, stream>>>(
            ui, ei, user_emb /*unused*/, ebuf, ubuf, nullptr, 0);
        norm_rows<<<N_USERS / 4, b256, 0, stream>>>(ubuf, acc_g, N_USERS, 2);
    }

    combine_att<<<N_USERS / 4, b256, 0, stream>>>(acc, user_ui, user_emb, out_user);
    proj_norm<<<dim3(N_USERS / 4, 2), b256, 0, stream>>>(
        user_ui, out_user, W1, b1, W2, b2, p1, p2);

    hipMemsetAsync(se_row, 0, 2 * N_USERS * 4, stream);
    lse_pass<<<N_USERS / IB, dim3(192), 0, stream>>>(p1, p2, se_row, diag, 1);
    lse_pass<<<N_USERS / IB, dim3(192), 0, stream>>>(p2, p1, se_col, nullptr, 0);
    loss_kernel<<<1, b256, 0, stream>>>(se_row, se_col, diag, out_loss);
}

// Round 2
// 716.576 us; speedup vs baseline: 2.1107x; 2.1107x over previous
//
#include <hip/hip_runtime.h>
#include <hip/hip_bf16.h>
#include <math.h>

#define N_USERS 8000
#define N_ENTITIES 32000
#define EMB 64
#define N_GROUPS 4
#define N_EDGES 200000

typedef __attribute__((ext_vector_type(8))) __bf16 bf16x8;
typedef __attribute__((ext_vector_type(16))) float f32x16;

// ---------------------------------------------------------------------------
// Edge scatter: one wave per edge, lane = embedding dim.
// ---------------------------------------------------------------------------
__global__ __launch_bounds__(256) void edge_scatter(
    const int* __restrict__ ui, const int* __restrict__ ei,
    const float* __restrict__ usrc, const float* __restrict__ esrc,
    float* __restrict__ udst, float* __restrict__ edst, int do_e)
{
    int e = blockIdx.x * 4 + (threadIdx.x >> 6);
    if (e >= N_EDGES) return;
    int lane = threadIdx.x & 63;
    int u = ui[e];
    int v = ei[e];
    atomicAdd(&udst[u * EMB + lane], esrc[v * EMB + lane]);
    if (do_e) atomicAdd(&edst[v * EMB + lane], usrc[u * EMB + lane]);
}

// ---------------------------------------------------------------------------
// Row L2-normalize in place; mode 1: acc = normalized, mode 2: acc += normalized
// ---------------------------------------------------------------------------
__global__ __launch_bounds__(256) void norm_rows(
    float* __restrict__ buf, float* __restrict__ acc, int rows, int mode)
{
    int row = blockIdx.x * 4 + (threadIdx.x >> 6);
    if (row >= rows) return;
    int lane = threadIdx.x & 63;
    float v = buf[row * EMB + lane];
    float ss = v * v;
    #pragma unroll
    for (int off = 1; off < 64; off <<= 1) ss += __shfl_xor(ss, off);
    float o = v / fmaxf(sqrtf(ss), 1e-12f);
    buf[row * EMB + lane] = o;
    if (mode == 1)      acc[row * EMB + lane] = o;
    else if (mode == 2) acc[row * EMB + lane] += o;
}

// ---------------------------------------------------------------------------
// Attention combine: scores -> softmax over 4 groups -> weighted sum + user_emb
// ---------------------------------------------------------------------------
__global__ __launch_bounds__(256) void combine_att(
    const float* __restrict__ acc, const float* __restrict__ uie,
    const float* __restrict__ uemb, float* __restrict__ out)
{
    int u = blockIdx.x * 4 + (threadIdx.x >> 6);
    if (u >= N_USERS) return;
    int lane = threadIdx.x & 63;
    float ue = uie[u * EMB + lane];
    float s[N_GROUPS];
    #pragma unroll
    for (int g = 0; g < N_GROUPS; ++g) {
        float p = acc[(size_t)g * N_USERS * EMB + u * EMB + lane] * ue;
        #pragma unroll
        for (int off = 1; off < 64; off <<= 1) p += __shfl_xor(p, off);
        s[g] = p;
    }
    float m = fmaxf(fmaxf(s[0], s[1]), fmaxf(s[2], s[3]));
    float att[N_GROUPS], tot = 0.f;
    #pragma unroll
    for (int g = 0; g < N_GROUPS; ++g) { att[g] = __expf(s[g] - m); tot += att[g]; }
    float inv = 1.0f / tot;
    float o = uemb[u * EMB + lane];
    #pragma unroll
    for (int g = 0; g < N_GROUPS; ++g)
        o += att[g] * inv * acc[(size_t)g * N_USERS * EMB + u * EMB + lane];
    out[u * EMB + lane] = o;
}

// ---------------------------------------------------------------------------
// proj(z) = elu(z@W1+b1)@W2 + b2, L2-normalize rows; emits fp32 AND bf16 copies.
// ---------------------------------------------------------------------------
__global__ __launch_bounds__(256) void proj_norm(
    const float* __restrict__ src1, const float* __restrict__ src2,
    const float* __restrict__ W1, const float* __restrict__ b1,
    const float* __restrict__ W2, const float* __restrict__ b2,
    float* __restrict__ dst1, float* __restrict__ dst2,
    __hip_bfloat16* __restrict__ dst1h, __hip_bfloat16* __restrict__ dst2h)
{
    __shared__ float W1s[EMB * EMB];
    __shared__ float W2s[EMB * EMB];
    __shared__ float zs[4][EMB];
    __shared__ float hs[4][EMB];
    const float* src = blockIdx.y ? src2 : src1;
    float* dst = blockIdx.y ? dst2 : dst1;
    __hip_bfloat16* dsth = blockIdx.y ? dst2h : dst1h;
    int t = threadIdx.x;
    for (int i = t; i < EMB * EMB; i += 256) { W1s[i] = W1[i]; W2s[i] = W2[i]; }
    int w = t >> 6, lane = t & 63;
    int row = blockIdx.x * 4 + w;
    float z = src[row * EMB + lane];
    zs[w][lane] = z;
    __syncthreads();
    float h = b1[lane];
    #pragma unroll
    for (int k = 0; k < EMB; ++k) h = fmaf(zs[w][k], W1s[k * EMB + lane], h);
    h = h > 0.f ? h : expm1f(h);
    hs[w][lane] = h;
    __syncthreads();
    float y = b2[lane];
    #pragma unroll
    for (int k = 0; k < EMB; ++k) y = fmaf(hs[w][k], W2s[k * EMB + lane], y);
    float ss = y * y;
    #pragma unroll
    for (int off = 1; off < 64; off <<= 1) ss += __shfl_xor(ss, off);
    float o = y / fmaxf(sqrtf(ss), 1e-12f);
    dst[row * EMB + lane] = o;
    dsth[row * EMB + lane] = __float2bfloat16(o);
}

// ---------------------------------------------------------------------------
// diag[i] = 2 * dot(p1_i, p2_i)  (fp32 exact)
// ---------------------------------------------------------------------------
__global__ __launch_bounds__(256) void diag_dot(
    const float* __restrict__ p1, const float* __restrict__ p2,
    float* __restrict__ diag)
{
    int row = blockIdx.x * 4 + (threadIdx.x >> 6);
    if (row >= N_USERS) return;
    int lane = threadIdx.x & 63;
    float v = p1[row * EMB + lane] * p2[row * EMB + lane];
    #pragma unroll
    for (int off = 1; off < 64; off <<= 1) v += __shfl_xor(v, off);
    if (lane == 0) diag[row] = v * 2.0f;
}

// ---------------------------------------------------------------------------
// MFMA LSE: one traversal of logits = 2 * A@B^T computes row and col exp-sum
// partials deterministically (no atomics).
// Wave = 32-row strip x 320-col chunk (10 tiles of 32x32, K=64 in 4 MFMAs).
//   rowp[chunk][i]  (25 x 8000)   colp[strip][j]  (250 x 8000)
// mfma_f32_32x32x16_bf16: A/B lane l -> row/col = l&31, k = (l>>5)*8 + j
//                         C/D: col = l&31, row = (r&3)+8*(r>>2)+4*(l>>5)
// ---------------------------------------------------------------------------
#define NCHUNK 25
#define TILES_PER_CHUNK 10
#define NWAVES (250 * NCHUNK)
__global__ __launch_bounds__(256) void lse_mfma(
    const __hip_bfloat16* __restrict__ Ah, const __hip_bfloat16* __restrict__ Bh,
    float* __restrict__ rowp, float* __restrict__ colp)
{
    int W = blockIdx.x * 4 + (threadIdx.x >> 6);
    if (W >= NWAVES) return;
    int lane = threadIdx.x & 63;
    int strip = W / NCHUNK;          // 0..249
    int chunk = W % NCHUNK;          // 0..24
    int i0 = strip * 32;
    int hl = lane >> 5;              // half-wave select
    int l31 = lane & 31;

    const bf16x8* A8 = (const bf16x8*)Ah;  // [8000][8] of bf16x8
    const bf16x8* B8 = (const bf16x8*)Bh;

    bf16x8 afrag[4];
    #pragma unroll
    for (int m = 0; m < 4; ++m)
        afrag[m] = A8[(i0 + l31) * 8 + m * 2 + hl];

    float rowacc[16];
    #pragma unroll
    for (int r = 0; r < 16; ++r) rowacc[r] = 0.f;

    for (int tj = 0; tj < TILES_PER_CHUNK; ++tj) {
        int j0 = chunk * (TILES_PER_CHUNK * 32) + tj * 32;
        bf16x8 bfrag[4];
        #pragma unroll
        for (int m = 0; m < 4; ++m)
            bfrag[m] = B8[(j0 + l31) * 8 + m * 2 + hl];
        f32x16 acc;
        #pragma unroll
        for (int r = 0; r < 16; ++r) acc[r] = 0.f;
        #pragma unroll
        for (int m = 0; m < 4; ++m)
            acc = __builtin_amdgcn_mfma_f32_32x32x16_bf16(afrag[m], bfrag[m], acc, 0, 0, 0);
        float csum = 0.f;
        #pragma unroll
        for (int r = 0; r < 16; ++r) {
            float e = __expf(acc[r] * 2.0f);   // logits = dot / tau, tau = 0.5
            rowacc[r] += e;
            csum += e;
        }
        csum += __shfl_xor(csum, 32);
        if (lane < 32) colp[strip * 8000 + j0 + lane] = csum;
    }
    // reduce rowacc across the 32 cols held by each half-wave
    #pragma unroll
    for (int r = 0; r < 16; ++r) {
        float v = rowacc[r];
        #pragma unroll
        for (int off = 1; off < 32; off <<= 1) v += __shfl_xor(v, off);
        if (l31 == 0)
            rowp[chunk * 8000 + i0 + (r & 3) + 8 * (r >> 2) + 4 * hl] = v;
    }
}

// ---------------------------------------------------------------------------
// se_row[i] = sum_c rowp[c][i]; se_col[j] = sum_s colp[s][j]
// ---------------------------------------------------------------------------
__global__ __launch_bounds__(256) void reduce_partials(
    const float* __restrict__ rowp, const float* __restrict__ colp,
    float* __restrict__ se_row, float* __restrict__ se_col)
{
    int id = blockIdx.x * 256 + threadIdx.x;
    if (id < N_USERS) {
        float s = 0.f;
        for (int c = 0; c < NCHUNK; ++c) s += rowp[c * 8000 + id];
        se_row[id] = s;
    } else if (id < 2 * N_USERS) {
        int j = id - N_USERS;
        float s = 0.f;
        for (int st = 0; st < 250; ++st) s += colp[st * 8000 + j];
        se_col[j] = s;
    }
}

// ---------------------------------------------------------------------------
// loss = mean_i( 0.5*(log(se_row)+log(se_col)) - diag )
// ---------------------------------------------------------------------------
__global__ __launch_bounds__(256) void loss_kernel(
    const float* __restrict__ se_row, const float* __restrict__ se_col,
    const float* __restrict__ diag, float* __restrict__ out)
{
    __shared__ float red[256];
    int t = threadIdx.x;
    float s = 0.f;
    for (int i = t; i < N_USERS; i += 256)
        s += 0.5f * (logf(se_row[i]) + logf(se_col[i])) - diag[i];
    red[t] = s;
    __syncthreads();
    for (int w = 128; w > 0; w >>= 1) {
        if (t < w) red[t] += red[t + w];
        __syncthreads();
    }
    if (t == 0) out[0] = red[0] / (float)N_USERS;
}

extern "C" void kernel_launch(void* const* d_in, const int* in_sizes, int n_in,
                              void* d_out, int out_size, void* d_ws, size_t ws_size,
                              hipStream_t stream)
{
    const float* user_emb   = (const float*)d_in[0];
    const float* user_ui    = (const float*)d_in[1];
    const float* entity_emb = (const float*)d_in[2];
    const float* W1 = (const float*)d_in[3];
    const float* b1 = (const float*)d_in[4];
    const float* W2 = (const float*)d_in[5];
    const float* b2 = (const float*)d_in[6];
    const int* ui_index = (const int*)d_in[7];
    const int* ei_index = (const int*)d_in[8];

    float* ws     = (float*)d_ws;
    float* acc    = ws;                       // 4 * 512000
    float* ubuf   = acc + 4 * 512000;         // 512000   (reused as rowp: 25*8000)
    float* ebuf   = ubuf + 512000;            // 2048000  (reused as colp: 250*8000)
    float* p1     = ebuf + 2048000;           // 512000
    float* p2     = p1 + 512000;              // 512000
    float* se_row = p2 + 512000;              // 8000
    float* se_col = se_row + 8000;            // 8000
    float* diag   = se_col + 8000;            // 8000
    __hip_bfloat16* p1h = (__hip_bfloat16*)(diag + 8000);   // 512000 bf16
    __hip_bfloat16* p2h = p1h + 512000;                     // 512000 bf16

    float* rowp = ubuf;
    float* colp = ebuf;

    float* out_user = (float*)d_out;          // 512000
    float* out_loss = out_user + 512000;      // 1

    dim3 b256(256);
    for (int g = 0; g < N_GROUPS; ++g) {
        const int* ui = ui_index + (size_t)g * N_EDGES;
        const int* ei = ei_index + (size_t)g * N_EDGES;
        float* acc_g = acc + (size_t)g * N_USERS * EMB;
        // hop 0: u_agg from entity_emb, e_int from user_emb
        hipMemsetAsync(ubuf, 0, (size_t)N_USERS * EMB * 4, stream);
        hipMemsetAsync(ebuf, 0, (size_t)N_ENTITIES * EMB * 4, stream);
        edge_scatter<<<(N_EDGES + 3) / 4, b256, 0, stream>>>(
            ui, ei, user_emb, entity_emb, ubuf, ebuf, 1);
        norm_rows<<<N_USERS / 4, b256, 0, stream>>>(ubuf, acc_g, N_USERS, 1);
        norm_rows<<<N_ENTITIES / 4, b256, 0, stream>>>(ebuf, nullptr, N_ENTITIES, 0);
        // hop 1: u_agg from normalized e_int (entity side never consumed again)
        hipMemsetAsync(ubuf, 0, (size_t)N_USERS * EMB * 4, stream);
        edge_scatter<<<(N_EDGES + 3) / 4, b256, 0, stream>>>(
            ui, ei, user_emb /*unused*/, ebuf, ubuf, nullptr, 0);
        norm_rows<<<N_USERS / 4, b256, 0, stream>>>(ubuf, acc_g, N_USERS, 2);
    }

    combine_att<<<N_USERS / 4, b256, 0, stream>>>(acc, user_ui, user_emb, out_user);
    proj_norm<<<dim3(N_USERS / 4, 2), b256, 0, stream>>>(
        user_ui, out_user, W1, b1, W2, b2, p1, p2, p1h, p2h);
    diag_dot<<<N_USERS / 4, b256, 0, stream>>>(p1, p2, diag);

    lse_mfma<<<(NWAVES + 3) / 4, b256, 0, stream>>>(p1h, p2h, rowp, colp);
    reduce_partials<<<(2 * N_USERS + 255) / 256, b256, 0, stream>>>(
        rowp, colp, se_row, se_col);
    loss_kernel<<<1, b256, 0, stream>>>(se_row, se_col, diag, out_loss);
}

// Round 3
// 496.529 us; speedup vs baseline: 3.0460x; 1.4432x over previous
//
#include <hip/hip_runtime.h>
#include <hip/hip_bf16.h>
#include <math.h>

#define N_USERS 8000
#define N_ENTITIES 32000
#define EMB 64
#define N_GROUPS 4
#define N_EDGES 200000

// CSR workspace strides (per group)
#define RPU_STRIDE 8192
#define RPE_STRIDE 32768

typedef __attribute__((ext_vector_type(8))) __bf16 bf16x8;
typedef __attribute__((ext_vector_type(16))) float f32x16;

// ---------------------------------------------------------------------------
// CSR build step 1: histogram of destinations for both directions, all groups.
// cur_u/cur_e must be zeroed beforehand.
// ---------------------------------------------------------------------------
__global__ __launch_bounds__(256) void build_hist(
    const int* __restrict__ ui_index, const int* __restrict__ ei_index,
    int* __restrict__ cur_u, int* __restrict__ cur_e)
{
    int g = blockIdx.y;
    const int* ui = ui_index + (size_t)g * N_EDGES;
    const int* ei = ei_index + (size_t)g * N_EDGES;
    int* cu = cur_u + g * RPU_STRIDE;
    int* ce = cur_e + g * RPE_STRIDE;
    for (int e = blockIdx.x * 256 + threadIdx.x; e < N_EDGES; e += gridDim.x * 256) {
        atomicAdd(&cu[ui[e]], 1);
        atomicAdd(&ce[ei[e]], 1);
    }
}

// ---------------------------------------------------------------------------
// CSR build step 2: exclusive scan of counts -> rowptr, and reset cursor to
// the same prefix (for the scatter pass). grid = (2 dirs, 4 groups).
// ---------------------------------------------------------------------------
__global__ __launch_bounds__(1024) void scan_counts(
    int* __restrict__ cur_u, int* __restrict__ cur_e,
    int* __restrict__ rp_u, int* __restrict__ rp_e)
{
    int dir = blockIdx.x, g = blockIdx.y;
    int n = dir ? N_ENTITIES : N_USERS;
    int* cnt = dir ? (cur_e + g * RPE_STRIDE) : (cur_u + g * RPU_STRIDE);
    int* rp  = dir ? (rp_e  + g * RPE_STRIDE) : (rp_u  + g * RPU_STRIDE);
    __shared__ int sums[1024];
    int t = threadIdx.x;
    int c = (n + 1023) >> 10;
    int lo = t * c, hi = min(lo + c, n);
    int s = 0;
    for (int i = lo; i < hi; ++i) s += cnt[i];
    sums[t] = s;
    __syncthreads();
    for (int off = 1; off < 1024; off <<= 1) {
        int v = (t >= off) ? sums[t - off] : 0;
        __syncthreads();
        sums[t] += v;
        __syncthreads();
    }
    int run = (t == 0) ? 0 : sums[t - 1];
    for (int i = lo; i < hi; ++i) {
        int cc = cnt[i];
        rp[i] = run;
        cnt[i] = run;   // cursor = prefix, for scatter
        run += cc;
    }
    if (hi == n) rp[n] = run;   // all writers write the same total
}

// ---------------------------------------------------------------------------
// CSR build step 3: scatter the OTHER endpoint into sorted order.
// ---------------------------------------------------------------------------
__global__ __launch_bounds__(256) void build_scatter(
    const int* __restrict__ ui_index, const int* __restrict__ ei_index,
    int* __restrict__ cur_u, int* __restrict__ cur_e,
    int* __restrict__ src_u, int* __restrict__ src_e)
{
    int g = blockIdx.y;
    const int* ui = ui_index + (size_t)g * N_EDGES;
    const int* ei = ei_index + (size_t)g * N_EDGES;
    int* cu = cur_u + g * RPU_STRIDE;
    int* ce = cur_e + g * RPE_STRIDE;
    int* su = src_u + (size_t)g * N_EDGES;
    int* se = src_e + (size_t)g * N_EDGES;
    for (int e = blockIdx.x * 256 + threadIdx.x; e < N_EDGES; e += gridDim.x * 256) {
        int u = ui[e], v = ei[e];
        int p = atomicAdd(&cu[u], 1); su[p] = v;
        int q = atomicAdd(&ce[v], 1); se[q] = u;
    }
}

// ---------------------------------------------------------------------------
// Fused gather-sum + L2-normalize. One wave per destination row, lane = dim.
// mode 0: out = norm(sum)       (entity side)
// mode 1: acc = norm(sum)       (user hop 0)
// mode 2: acc += norm(sum)      (user hop 1)
// Source indices are wave-uniform scalar loads; 4-deep unroll for MLP.
// ---------------------------------------------------------------------------
__global__ __launch_bounds__(256) void agg_norm(
    const int* __restrict__ rowptr, const int* __restrict__ srcidx,
    const float* __restrict__ table, float* __restrict__ out,
    float* __restrict__ acc, int nrows, int mode)
{
    int row = blockIdx.x * 4 + (threadIdx.x >> 6);
    if (row >= nrows) return;
    int lane = threadIdx.x & 63;
    int start = rowptr[row], end = rowptr[row + 1];
    float s0 = 0.f, s1 = 0.f, s2 = 0.f, s3 = 0.f;
    int k = start;
    for (; k + 3 < end; k += 4) {
        int i0 = srcidx[k], i1 = srcidx[k + 1], i2 = srcidx[k + 2], i3 = srcidx[k + 3];
        s0 += table[i0 * EMB + lane];
        s1 += table[i1 * EMB + lane];
        s2 += table[i2 * EMB + lane];
        s3 += table[i3 * EMB + lane];
    }
    for (; k < end; ++k) s0 += table[srcidx[k] * EMB + lane];
    float v = (s0 + s1) + (s2 + s3);
    float ss = v * v;
    #pragma unroll
    for (int off = 1; off < 64; off <<= 1) ss += __shfl_xor(ss, off);
    float o = v / fmaxf(sqrtf(ss), 1e-12f);
    if (mode == 0)      out[row * EMB + lane] = o;
    else if (mode == 1) acc[row * EMB + lane] = o;
    else                acc[row * EMB + lane] += o;
}

// ---------------------------------------------------------------------------
// Attention combine: scores -> softmax over 4 groups -> weighted sum + user_emb
// ---------------------------------------------------------------------------
__global__ __launch_bounds__(256) void combine_att(
    const float* __restrict__ acc, const float* __restrict__ uie,
    const float* __restrict__ uemb, float* __restrict__ out)
{
    int u = blockIdx.x * 4 + (threadIdx.x >> 6);
    if (u >= N_USERS) return;
    int lane = threadIdx.x & 63;
    float ue = uie[u * EMB + lane];
    float s[N_GROUPS];
    #pragma unroll
    for (int g = 0; g < N_GROUPS; ++g) {
        float p = acc[(size_t)g * N_USERS * EMB + u * EMB + lane] * ue;
        #pragma unroll
        for (int off = 1; off < 64; off <<= 1) p += __shfl_xor(p, off);
        s[g] = p;
    }
    float m = fmaxf(fmaxf(s[0], s[1]), fmaxf(s[2], s[3]));
    float att[N_GROUPS], tot = 0.f;
    #pragma unroll
    for (int g = 0; g < N_GROUPS; ++g) { att[g] = __expf(s[g] - m); tot += att[g]; }
    float inv = 1.0f / tot;
    float o = uemb[u * EMB + lane];
    #pragma unroll
    for (int g = 0; g < N_GROUPS; ++g)
        o += att[g] * inv * acc[(size_t)g * N_USERS * EMB + u * EMB + lane];
    out[u * EMB + lane] = o;
}

// ---------------------------------------------------------------------------
// proj(z) = elu(z@W1+b1)@W2 + b2, L2-normalize rows; emits fp32 AND bf16 copies.
// ---------------------------------------------------------------------------
__global__ __launch_bounds__(256) void proj_norm(
    const float* __restrict__ src1, const float* __restrict__ src2,
    const float* __restrict__ W1, const float* __restrict__ b1,
    const float* __restrict__ W2, const float* __restrict__ b2,
    float* __restrict__ dst1, float* __restrict__ dst2,
    __hip_bfloat16* __restrict__ dst1h, __hip_bfloat16* __restrict__ dst2h)
{
    __shared__ float W1s[EMB * EMB];
    __shared__ float W2s[EMB * EMB];
    __shared__ float zs[4][EMB];
    __shared__ float hs[4][EMB];
    const float* src = blockIdx.y ? src2 : src1;
    float* dst = blockIdx.y ? dst2 : dst1;
    __hip_bfloat16* dsth = blockIdx.y ? dst2h : dst1h;
    int t = threadIdx.x;
    for (int i = t; i < EMB * EMB; i += 256) { W1s[i] = W1[i]; W2s[i] = W2[i]; }
    int w = t >> 6, lane = t & 63;
    int row = blockIdx.x * 4 + w;
    float z = src[row * EMB + lane];
    zs[w][lane] = z;
    __syncthreads();
    float h = b1[lane];
    #pragma unroll
    for (int k = 0; k < EMB; ++k) h = fmaf(zs[w][k], W1s[k * EMB + lane], h);
    h = h > 0.f ? h : expm1f(h);
    hs[w][lane] = h;
    __syncthreads();
    float y = b2[lane];
    #pragma unroll
    for (int k = 0; k < EMB; ++k) y = fmaf(hs[w][k], W2s[k * EMB + lane], y);
    float ss = y * y;
    #pragma unroll
    for (int off = 1; off < 64; off <<= 1) ss += __shfl_xor(ss, off);
    float o = y / fmaxf(sqrtf(ss), 1e-12f);
    dst[row * EMB + lane] = o;
    dsth[row * EMB + lane] = __float2bfloat16(o);
}

// ---------------------------------------------------------------------------
// diag[i] = 2 * dot(p1_i, p2_i)  (fp32 exact)
// ---------------------------------------------------------------------------
__global__ __launch_bounds__(256) void diag_dot(
    const float* __restrict__ p1, const float* __restrict__ p2,
    float* __restrict__ diag)
{
    int row = blockIdx.x * 4 + (threadIdx.x >> 6);
    if (row >= N_USERS) return;
    int lane = threadIdx.x & 63;
    float v = p1[row * EMB + lane] * p2[row * EMB + lane];
    #pragma unroll
    for (int off = 1; off < 64; off <<= 1) v += __shfl_xor(v, off);
    if (lane == 0) diag[row] = v * 2.0f;
}

// ---------------------------------------------------------------------------
// MFMA LSE: one traversal of logits = 2 * A@B^T computes row and col exp-sum
// partials deterministically (no atomics).
// ---------------------------------------------------------------------------
#define NCHUNK 25
#define TILES_PER_CHUNK 10
#define NWAVES (250 * NCHUNK)
__global__ __launch_bounds__(256) void lse_mfma(
    const __hip_bfloat16* __restrict__ Ah, const __hip_bfloat16* __restrict__ Bh,
    float* __restrict__ rowp, float* __restrict__ colp)
{
    int W = blockIdx.x * 4 + (threadIdx.x >> 6);
    if (W >= NWAVES) return;
    int lane = threadIdx.x & 63;
    int strip = W / NCHUNK;
    int chunk = W % NCHUNK;
    int i0 = strip * 32;
    int hl = lane >> 5;
    int l31 = lane & 31;

    const bf16x8* A8 = (const bf16x8*)Ah;
    const bf16x8* B8 = (const bf16x8*)Bh;

    bf16x8 afrag[4];
    #pragma unroll
    for (int m = 0; m < 4; ++m)
        afrag[m] = A8[(i0 + l31) * 8 + m * 2 + hl];

    float rowacc[16];
    #pragma unroll
    for (int r = 0; r < 16; ++r) rowacc[r] = 0.f;

    for (int tj = 0; tj < TILES_PER_CHUNK; ++tj) {
        int j0 = chunk * (TILES_PER_CHUNK * 32) + tj * 32;
        bf16x8 bfrag[4];
        #pragma unroll
        for (int m = 0; m < 4; ++m)
            bfrag[m] = B8[(j0 + l31) * 8 + m * 2 + hl];
        f32x16 acc;
        #pragma unroll
        for (int r = 0; r < 16; ++r) acc[r] = 0.f;
        #pragma unroll
        for (int m = 0; m < 4; ++m)
            acc = __builtin_amdgcn_mfma_f32_32x32x16_bf16(afrag[m], bfrag[m], acc, 0, 0, 0);
        float csum = 0.f;
        #pragma unroll
        for (int r = 0; r < 16; ++r) {
            float e = __expf(acc[r] * 2.0f);
            rowacc[r] += e;
            csum += e;
        }
        csum += __shfl_xor(csum, 32);
        if (lane < 32) colp[strip * 8000 + j0 + lane] = csum;
    }
    #pragma unroll
    for (int r = 0; r < 16; ++r) {
        float v = rowacc[r];
        #pragma unroll
        for (int off = 1; off < 32; off <<= 1) v += __shfl_xor(v, off);
        if (l31 == 0)
            rowp[chunk * 8000 + i0 + (r & 3) + 8 * (r >> 2) + 4 * hl] = v;
    }
}

// ---------------------------------------------------------------------------
// se_row[i] = sum_c rowp[c][i]; se_col[j] = sum_s colp[s][j]
// ---------------------------------------------------------------------------
__global__ __launch_bounds__(256) void reduce_partials(
    const float* __restrict__ rowp, const float* __restrict__ colp,
    float* __restrict__ se_row, float* __restrict__ se_col)
{
    int id = blockIdx.x * 256 + threadIdx.x;
    if (id < N_USERS) {
        float s = 0.f;
        for (int c = 0; c < NCHUNK; ++c) s += rowp[c * 8000 + id];
        se_row[id] = s;
    } else if (id < 2 * N_USERS) {
        int j = id - N_USERS;
        float s = 0.f;
        for (int st = 0; st < 250; ++st) s += colp[st * 8000 + j];
        se_col[j] = s;
    }
}

// ---------------------------------------------------------------------------
// loss = mean_i( 0.5*(log(se_row)+log(se_col)) - diag )
// ---------------------------------------------------------------------------
__global__ __launch_bounds__(256) void loss_kernel(
    const float* __restrict__ se_row, const float* __restrict__ se_col,
    const float* __restrict__ diag, float* __restrict__ out)
{
    __shared__ float red[256];
    int t = threadIdx.x;
    float s = 0.f;
    for (int i = t; i < N_USERS; i += 256)
        s += 0.5f * (logf(se_row[i]) + logf(se_col[i])) - diag[i];
    red[t] = s;
    __syncthreads();
    for (int w = 128; w > 0; w >>= 1) {
        if (t < w) red[t] += red[t + w];
        __syncthreads();
    }
    if (t == 0) out[0] = red[0] / (float)N_USERS;
}

extern "C" void kernel_launch(void* const* d_in, const int* in_sizes, int n_in,
                              void* d_out, int out_size, void* d_ws, size_t ws_size,
                              hipStream_t stream)
{
    const float* user_emb   = (const float*)d_in[0];
    const float* user_ui    = (const float*)d_in[1];
    const float* entity_emb = (const float*)d_in[2];
    const float* W1 = (const float*)d_in[3];
    const float* b1 = (const float*)d_in[4];
    const float* W2 = (const float*)d_in[5];
    const float* b2 = (const float*)d_in[6];
    const int* ui_index = (const int*)d_in[7];
    const int* ei_index = (const int*)d_in[8];

    float* ws     = (float*)d_ws;
    float* acc    = ws;                        // 4*512000 (later: rowp 25*8000)
    float* ebuf   = acc + 4 * 512000;          // 2048000  (later: colp 250*8000)
    float* p1     = ebuf + 2048000;            // 512000
    float* p2     = p1 + 512000;               // 512000
    float* se_row = p2 + 512000;               // 8000
    float* se_col = se_row + 8000;             // 8000
    float* diag   = se_col + 8000;             // 8000
    __hip_bfloat16* p1h = (__hip_bfloat16*)(diag + 8000);   // 512000 bf16
    __hip_bfloat16* p2h = p1h + 512000;                     // 512000 bf16
    // integer CSR region
    int* cur_u = (int*)(p2h + 512000);          // 4*8192
    int* cur_e = cur_u + 4 * RPU_STRIDE;        // 4*32768
    int* rp_u  = cur_e + 4 * RPE_STRIDE;        // 4*8192
    int* rp_e  = rp_u + 4 * RPU_STRIDE;         // 4*32768
    int* src_u = rp_e + 4 * RPE_STRIDE;         // 4*200000
    int* src_e = src_u + 4 * N_EDGES;           // 4*200000

    float* rowp = acc;
    float* colp = ebuf;

    float* out_user = (float*)d_out;            // 512000
    float* out_loss = out_user + 512000;        // 1

    dim3 b256(256);

    // ---- CSR build for all 4 groups, both directions (4 dispatches) ----
    hipMemsetAsync(cur_u, 0, (size_t)(4 * RPU_STRIDE + 4 * RPE_STRIDE) * 4, stream);
    build_hist<<<dim3(512, 4), b256, 0, stream>>>(ui_index, ei_index, cur_u, cur_e);
    scan_counts<<<dim3(2, 4), dim3(1024), 0, stream>>>(cur_u, cur_e, rp_u, rp_e);
    build_scatter<<<dim3(512, 4), b256, 0, stream>>>(
        ui_index, ei_index, cur_u, cur_e, src_u, src_e);

    // ---- graph propagation: gather-sum + fused norm, no float atomics ----
    for (int g = 0; g < N_GROUPS; ++g) {
        const int* rpu = rp_u + g * RPU_STRIDE;
        const int* rpe = rp_e + g * RPE_STRIDE;
        const int* su  = src_u + (size_t)g * N_EDGES;
        const int* se  = src_e + (size_t)g * N_EDGES;
        float* acc_g = acc + (size_t)g * N_USERS * EMB;
        // hop0 entity side: e_int = norm(sum user_emb[ui])
        agg_norm<<<N_ENTITIES / 4, b256, 0, stream>>>(
            rpe, se, user_emb, ebuf, nullptr, N_ENTITIES, 0);
        // hop0 user side: acc_g = norm(sum entity_emb[ei])
        agg_norm<<<N_USERS / 4, b256, 0, stream>>>(
            rpu, su, entity_emb, nullptr, acc_g, N_USERS, 1);
        // hop1 user side: acc_g += norm(sum ebuf[ei])
        agg_norm<<<N_USERS / 4, b256, 0, stream>>>(
            rpu, su, ebuf, nullptr, acc_g, N_USERS, 2);
    }

    combine_att<<<N_USERS / 4, b256, 0, stream>>>(acc, user_ui, user_emb, out_user);
    proj_norm<<<dim3(N_USERS / 4, 2), b256, 0, stream>>>(
        user_ui, out_user, W1, b1, W2, b2, p1, p2, p1h, p2h);
    diag_dot<<<N_USERS / 4, b256, 0, stream>>>(p1, p2, diag);

    lse_mfma<<<(NWAVES + 3) / 4, b256, 0, stream>>>(p1h, p2h, rowp, colp);
    reduce_partials<<<(2 * N_USERS + 255) / 256, b256, 0, stream>>>(
        rowp, colp, se_row, se_col);
    loss_kernel<<<1, b256, 0, stream>>>(se_row, se_col, diag, out_loss);
}

// Round 4
// 416.232 us; speedup vs baseline: 3.6337x; 1.1929x over previous
//
#include <hip/hip_runtime.h>
#include <hip/hip_bf16.h>
#include <math.h>

#define N_USERS 8000
#define N_ENTITIES 32000
#define EMB 64
#define N_GROUPS 4
#define N_EDGES 200000

#define HEADU_STRIDE 32768     // 8000 rows * 4 parity chains, padded
#define HEADE_STRIDE 131072    // 32000 rows * 4 parity chains, padded

typedef __attribute__((ext_vector_type(8))) __bf16 bf16x8;
typedef __attribute__((ext_vector_type(16))) float f32x16;

// ---------------------------------------------------------------------------
// Linked-list adjacency build: next[e] = atomicExch(&head[dest*4 + (e&3)], e)
// All writes coalesced (indexed by e); atomics hit small L2-resident tables.
// ---------------------------------------------------------------------------
__global__ __launch_bounds__(256) void build_links(
    const int* __restrict__ ui_index, const int* __restrict__ ei_index,
    int* __restrict__ head_u, int* __restrict__ head_e,
    int* __restrict__ next_u, int* __restrict__ next_e)
{
    int g = blockIdx.y;
    const int* ui = ui_index + (size_t)g * N_EDGES;
    const int* ei = ei_index + (size_t)g * N_EDGES;
    int* hu = head_u + (size_t)g * HEADU_STRIDE;
    int* he = head_e + (size_t)g * HEADE_STRIDE;
    int* nu = next_u + (size_t)g * N_EDGES;
    int* ne = next_e + (size_t)g * N_EDGES;
    int e = blockIdx.x * 256 + threadIdx.x;
    if (e >= N_EDGES) return;
    int u = ui[e], v = ei[e];
    nu[e] = atomicExch(&hu[(u << 2) | (e & 3)], e);
    ne[e] = atomicExch(&he[(v << 2) | (e & 3)], e);
}

// ---------------------------------------------------------------------------
// Walk the 4 parity chains of one row, summing table rows. Lane = dim.
// 4 independent dependency chains overlap their L2 latencies.
// ---------------------------------------------------------------------------
__device__ __forceinline__ float walk_sum(
    const int* __restrict__ head4, const int* __restrict__ nxt,
    const int* __restrict__ srcarr, const float* __restrict__ table,
    int row, int lane)
{
    int e0 = head4[row * 4 + 0], e1 = head4[row * 4 + 1];
    int e2 = head4[row * 4 + 2], e3 = head4[row * 4 + 3];
    float s0 = 0.f, s1 = 0.f, s2 = 0.f, s3 = 0.f;
    while ((e0 & e1 & e2 & e3) >= 0) {   // loop while ANY chain active
        if (e0 >= 0) { int n = nxt[e0]; s0 += table[srcarr[e0] * EMB + lane]; e0 = n; }
        if (e1 >= 0) { int n = nxt[e1]; s1 += table[srcarr[e1] * EMB + lane]; e1 = n; }
        if (e2 >= 0) { int n = nxt[e2]; s2 += table[srcarr[e2] * EMB + lane]; e2 = n; }
        if (e3 >= 0) { int n = nxt[e3]; s3 += table[srcarr[e3] * EMB + lane]; e3 = n; }
    }
    return (s0 + s1) + (s2 + s3);
}

__device__ __forceinline__ float l2n(float v) {
    float ss = v * v;
    #pragma unroll
    for (int off = 1; off < 64; off <<= 1) ss += __shfl_xor(ss, off);
    return v / fmaxf(sqrtf(ss), 1e-12f);
}

// ---------------------------------------------------------------------------
// hop0 for one-or-all groups: y==0 entity side (ebuf = norm(sum user_emb)),
// y==1 user side (acc[g] = norm(sum entity_emb)). z = group-within-launch.
// ---------------------------------------------------------------------------
__global__ __launch_bounds__(256) void agg_hop0(
    const int* __restrict__ head_u, const int* __restrict__ head_e,
    const int* __restrict__ next_u, const int* __restrict__ next_e,
    const int* __restrict__ ui_index, const int* __restrict__ ei_index,
    const float* __restrict__ user_emb, const float* __restrict__ entity_emb,
    float* __restrict__ ebuf, float* __restrict__ acc, int gbase)
{
    int gz = blockIdx.z;
    int g = gbase + gz;
    int row = blockIdx.x * 4 + (threadIdx.x >> 6);
    int lane = threadIdx.x & 63;
    if (blockIdx.y == 0) {
        if (row >= N_ENTITIES) return;
        float v = walk_sum(head_e + (size_t)g * HEADE_STRIDE,
                           next_e + (size_t)g * N_EDGES,
                           ui_index + (size_t)g * N_EDGES, user_emb, row, lane);
        ebuf[(size_t)gz * N_ENTITIES * EMB + row * EMB + lane] = l2n(v);
    } else {
        if (row >= N_USERS) return;
        float v = walk_sum(head_u + (size_t)g * HEADU_STRIDE,
                           next_u + (size_t)g * N_EDGES,
                           ei_index + (size_t)g * N_EDGES, entity_emb, row, lane);
        acc[(size_t)g * N_USERS * EMB + row * EMB + lane] = l2n(v);
    }
}

// ---------------------------------------------------------------------------
// hop1 user side: acc[g] += norm(sum ebuf[gz][ei])
// ---------------------------------------------------------------------------
__global__ __launch_bounds__(256) void agg_hop1(
    const int* __restrict__ head_u, const int* __restrict__ next_u,
    const int* __restrict__ ei_index, const float* __restrict__ ebuf,
    float* __restrict__ acc, int gbase)
{
    int gz = blockIdx.z;
    int g = gbase + gz;
    int row = blockIdx.x * 4 + (threadIdx.x >> 6);
    int lane = threadIdx.x & 63;
    if (row >= N_USERS) return;
    float v = walk_sum(head_u + (size_t)g * HEADU_STRIDE,
                       next_u + (size_t)g * N_EDGES,
                       ei_index + (size_t)g * N_EDGES,
                       ebuf + (size_t)gz * N_ENTITIES * EMB, row, lane);
    acc[(size_t)g * N_USERS * EMB + row * EMB + lane] += l2n(v);
}

// ---------------------------------------------------------------------------
// Attention combine: scores -> softmax over 4 groups -> weighted sum + user_emb
// ---------------------------------------------------------------------------
__global__ __launch_bounds__(256) void combine_att(
    const float* __restrict__ acc, const float* __restrict__ uie,
    const float* __restrict__ uemb, float* __restrict__ out)
{
    int u = blockIdx.x * 4 + (threadIdx.x >> 6);
    if (u >= N_USERS) return;
    int lane = threadIdx.x & 63;
    float ue = uie[u * EMB + lane];
    float s[N_GROUPS];
    #pragma unroll
    for (int g = 0; g < N_GROUPS; ++g) {
        float p = acc[(size_t)g * N_USERS * EMB + u * EMB + lane] * ue;
        #pragma unroll
        for (int off = 1; off < 64; off <<= 1) p += __shfl_xor(p, off);
        s[g] = p;
    }
    float m = fmaxf(fmaxf(s[0], s[1]), fmaxf(s[2], s[3]));
    float att[N_GROUPS], tot = 0.f;
    #pragma unroll
    for (int g = 0; g < N_GROUPS; ++g) { att[g] = __expf(s[g] - m); tot += att[g]; }
    float inv = 1.0f / tot;
    float o = uemb[u * EMB + lane];
    #pragma unroll
    for (int g = 0; g < N_GROUPS; ++g)
        o += att[g] * inv * acc[(size_t)g * N_USERS * EMB + u * EMB + lane];
    out[u * EMB + lane] = o;
}

// ---------------------------------------------------------------------------
// proj(z) = elu(z@W1+b1)@W2 + b2, L2-normalize rows; emits fp32 AND bf16 copies.
// ---------------------------------------------------------------------------
__global__ __launch_bounds__(256) void proj_norm(
    const float* __restrict__ src1, const float* __restrict__ src2,
    const float* __restrict__ W1, const float* __restrict__ b1,
    const float* __restrict__ W2, const float* __restrict__ b2,
    float* __restrict__ dst1, float* __restrict__ dst2,
    __hip_bfloat16* __restrict__ dst1h, __hip_bfloat16* __restrict__ dst2h)
{
    __shared__ float W1s[EMB * EMB];
    __shared__ float W2s[EMB * EMB];
    __shared__ float zs[4][EMB];
    __shared__ float hs[4][EMB];
    const float* src = blockIdx.y ? src2 : src1;
    float* dst = blockIdx.y ? dst2 : dst1;
    __hip_bfloat16* dsth = blockIdx.y ? dst2h : dst1h;
    int t = threadIdx.x;
    for (int i = t; i < EMB * EMB; i += 256) { W1s[i] = W1[i]; W2s[i] = W2[i]; }
    int w = t >> 6, lane = t & 63;
    int row = blockIdx.x * 4 + w;
    float z = src[row * EMB + lane];
    zs[w][lane] = z;
    __syncthreads();
    float h = b1[lane];
    #pragma unroll
    for (int k = 0; k < EMB; ++k) h = fmaf(zs[w][k], W1s[k * EMB + lane], h);
    h = h > 0.f ? h : expm1f(h);
    hs[w][lane] = h;
    __syncthreads();
    float y = b2[lane];
    #pragma unroll
    for (int k = 0; k < EMB; ++k) y = fmaf(hs[w][k], W2s[k * EMB + lane], y);
    float ss = y * y;
    #pragma unroll
    for (int off = 1; off < 64; off <<= 1) ss += __shfl_xor(ss, off);
    float o = y / fmaxf(sqrtf(ss), 1e-12f);
    dst[row * EMB + lane] = o;
    dsth[row * EMB + lane] = __float2bfloat16(o);
}

// ---------------------------------------------------------------------------
// diag[i] = 2 * dot(p1_i, p2_i)  (fp32 exact)
// ---------------------------------------------------------------------------
__global__ __launch_bounds__(256) void diag_dot(
    const float* __restrict__ p1, const float* __restrict__ p2,
    float* __restrict__ diag)
{
    int row = blockIdx.x * 4 + (threadIdx.x >> 6);
    if (row >= N_USERS) return;
    int lane = threadIdx.x & 63;
    float v = p1[row * EMB + lane] * p2[row * EMB + lane];
    #pragma unroll
    for (int off = 1; off < 64; off <<= 1) v += __shfl_xor(v, off);
    if (lane == 0) diag[row] = v * 2.0f;
}

// ---------------------------------------------------------------------------
// MFMA LSE: one traversal of logits = 2 * A@B^T -> row & col exp-sum partials.
// ---------------------------------------------------------------------------
#define NCHUNK 25
#define TILES_PER_CHUNK 10
#define NWAVES (250 * NCHUNK)
__global__ __launch_bounds__(256) void lse_mfma(
    const __hip_bfloat16* __restrict__ Ah, const __hip_bfloat16* __restrict__ Bh,
    float* __restrict__ rowp, float* __restrict__ colp)
{
    int W = blockIdx.x * 4 + (threadIdx.x >> 6);
    if (W >= NWAVES) return;
    int lane = threadIdx.x & 63;
    int strip = W / NCHUNK;
    int chunk = W % NCHUNK;
    int i0 = strip * 32;
    int hl = lane >> 5;
    int l31 = lane & 31;

    const bf16x8* A8 = (const bf16x8*)Ah;
    const bf16x8* B8 = (const bf16x8*)Bh;

    bf16x8 afrag[4];
    #pragma unroll
    for (int m = 0; m < 4; ++m)
        afrag[m] = A8[(i0 + l31) * 8 + m * 2 + hl];

    float rowacc[16];
    #pragma unroll
    for (int r = 0; r < 16; ++r) rowacc[r] = 0.f;

    for (int tj = 0; tj < TILES_PER_CHUNK; ++tj) {
        int j0 = chunk * (TILES_PER_CHUNK * 32) + tj * 32;
        bf16x8 bfrag[4];
        #pragma unroll
        for (int m = 0; m < 4; ++m)
            bfrag[m] = B8[(j0 + l31) * 8 + m * 2 + hl];
        f32x16 acc;
        #pragma unroll
        for (int r = 0; r < 16; ++r) acc[r] = 0.f;
        #pragma unroll
        for (int m = 0; m < 4; ++m)
            acc = __builtin_amdgcn_mfma_f32_32x32x16_bf16(afrag[m], bfrag[m], acc, 0, 0, 0);
        float csum = 0.f;
        #pragma unroll
        for (int r = 0; r < 16; ++r) {
            float e = __expf(acc[r] * 2.0f);
            rowacc[r] += e;
            csum += e;
        }
        csum += __shfl_xor(csum, 32);
        if (lane < 32) colp[strip * 8000 + j0 + lane] = csum;
    }
    #pragma unroll
    for (int r = 0; r < 16; ++r) {
        float v = rowacc[r];
        #pragma unroll
        for (int off = 1; off < 32; off <<= 1) v += __shfl_xor(v, off);
        if (l31 == 0)
            rowp[chunk * 8000 + i0 + (r & 3) + 8 * (r >> 2) + 4 * hl] = v;
    }
}

// ---------------------------------------------------------------------------
// se_row[i] = sum_c rowp[c][i]; se_col[j] = sum_s colp[s][j]
// ---------------------------------------------------------------------------
__global__ __launch_bounds__(256) void reduce_partials(
    const float* __restrict__ rowp, const float* __restrict__ colp,
    float* __restrict__ se_row, float* __restrict__ se_col)
{
    int id = blockIdx.x * 256 + threadIdx.x;
    if (id < N_USERS) {
        float s = 0.f;
        for (int c = 0; c < NCHUNK; ++c) s += rowp[c * 8000 + id];
        se_row[id] = s;
    } else if (id < 2 * N_USERS) {
        int j = id - N_USERS;
        float s = 0.f;
        for (int st = 0; st < 250; ++st) s += colp[st * 8000 + j];
        se_col[j] = s;
    }
}

// ---------------------------------------------------------------------------
// loss = mean_i( 0.5*(log(se_row)+log(se_col)) - diag )
// ---------------------------------------------------------------------------
__global__ __launch_bounds__(256) void loss_kernel(
    const float* __restrict__ se_row, const float* __restrict__ se_col,
    const float* __restrict__ diag, float* __restrict__ out)
{
    __shared__ float red[256];
    int t = threadIdx.x;
    float s = 0.f;
    for (int i = t; i < N_USERS; i += 256)
        s += 0.5f * (logf(se_row[i]) + logf(se_col[i])) - diag[i];
    red[t] = s;
    __syncthreads();
    for (int w = 128; w > 0; w >>= 1) {
        if (t < w) red[t] += red[t + w];
        __syncthreads();
    }
    if (t == 0) out[0] = red[0] / (float)N_USERS;
}

extern "C" void kernel_launch(void* const* d_in, const int* in_sizes, int n_in,
                              void* d_out, int out_size, void* d_ws, size_t ws_size,
                              hipStream_t stream)
{
    const float* user_emb   = (const float*)d_in[0];
    const float* user_ui    = (const float*)d_in[1];
    const float* entity_emb = (const float*)d_in[2];
    const float* W1 = (const float*)d_in[3];
    const float* b1 = (const float*)d_in[4];
    const float* W2 = (const float*)d_in[5];
    const float* b2 = (const float*)d_in[6];
    const int* ui_index = (const int*)d_in[7];
    const int* ei_index = (const int*)d_in[8];

    float* ws = (float*)d_ws;
    // acc region (2,048,000 f); after combine_att it is reused for
    // rowp / p1 / p2 / p1h / p2h (all consumers ordered on the stream).
    float* acc    = ws;
    float* rowp   = acc;                       // 25*8000 = 200,000 f
    float* p1     = acc + 204800;              // 512,000 f
    float* p2     = acc + 716800;              // 512,000 f
    __hip_bfloat16* p1h = (__hip_bfloat16*)(acc + 1228800);  // 512,000 bf16
    __hip_bfloat16* p2h = (__hip_bfloat16*)(acc + 1484800);  // 512,000 bf16
    float* se_row = ws + 2048000;              // 8,000
    float* se_col = se_row + 8000;             // 8,000
    float* diag   = se_col + 8000;             // 8,000
    int* head_u = (int*)(diag + 8000);         // 4 * 32768
    int* head_e = head_u + 4 * HEADU_STRIDE;   // 4 * 131072
    int* next_u = head_e + 4 * HEADE_STRIDE;   // 4 * 200000
    int* next_e = next_u + 4 * N_EDGES;        // 4 * 200000
    float* ebuf = (float*)(next_e + 4 * N_EDGES);

    // fused mode needs 4 entity buffers: (4,327,360 + 4*2,048,000) floats
    const size_t FUSED_BYTES = (size_t)(4327360 + 4 * 2048000) * 4;
    int nG = (ws_size >= FUSED_BYTES) ? N_GROUPS : 1;
    float* colp = ebuf;                        // >= 2,000,000 f in both modes

    float* out_user = (float*)d_out;           // 512,000
    float* out_loss = out_user + 512000;       // 1

    dim3 b256(256);

    // heads := -1 (head_u and head_e are contiguous)
    hipMemsetAsync(head_u, 0xFF,
                   (size_t)(4 * HEADU_STRIDE + 4 * HEADE_STRIDE) * 4, stream);
    build_links<<<dim3((N_EDGES + 255) / 256, N_GROUPS), b256, 0, stream>>>(
        ui_index, ei_index, head_u, head_e, next_u, next_e);

    for (int gbase = 0; gbase < N_GROUPS; gbase += nG) {
        agg_hop0<<<dim3(N_ENTITIES / 4, 2, nG), b256, 0, stream>>>(
            head_u, head_e, next_u, next_e, ui_index, ei_index,
            user_emb, entity_emb, ebuf, acc, gbase);
        agg_hop1<<<dim3(N_USERS / 4, 1, nG), b256, 0, stream>>>(
            head_u, next_u, ei_index, ebuf, acc, gbase);
    }

    combine_att<<<N_USERS / 4, b256, 0, stream>>>(acc, user_ui, user_emb, out_user);
    proj_norm<<<dim3(N_USERS / 4, 2), b256, 0, stream>>>(
        user_ui, out_user, W1, b1, W2, b2, p1, p2, p1h, p2h);
    diag_dot<<<N_USERS / 4, b256, 0, stream>>>(p1, p2, diag);

    lse_mfma<<<(NWAVES + 3) / 4, b256, 0, stream>>>(p1h, p2h, rowp, colp);
    reduce_partials<<<(2 * N_USERS + 255) / 256, b256, 0, stream>>>(
        rowp, colp, se_row, se_col);
    loss_kernel<<<1, b256, 0, stream>>>(se_row, se_col, diag, out_loss);
}

// Round 5
// 409.788 us; speedup vs baseline: 3.6908x; 1.0157x over previous
//
#include <hip/hip_runtime.h>
#include <hip/hip_bf16.h>
#include <math.h>

#define N_USERS 8000
#define N_ENTITIES 32000
#define EMB 64
#define N_GROUPS 4
#define N_EDGES 200000

#define HEADU_STRIDE 32768     // 8000 rows * 4 parity chains, padded
#define HEADE_STRIDE 131072    // 32000 rows * 4 parity chains, padded

typedef __attribute__((ext_vector_type(8))) __bf16 bf16x8;
typedef __attribute__((ext_vector_type(16))) float f32x16;

static __device__ __forceinline__ float bf2f(unsigned short u) {
    union { unsigned int i; float f; } x; x.i = ((unsigned int)u) << 16; return x.f;
}
static __device__ __forceinline__ unsigned short f2bf(float f) {
    union { float f; unsigned int i; } x; x.f = f;
    return (unsigned short)((x.i + 0x7FFF + ((x.i >> 16) & 1)) >> 16);
}

// ---------------------------------------------------------------------------
// Convert user_emb (512,000 f) and entity_emb (2,048,000 f) to bf16 tables.
// ---------------------------------------------------------------------------
__global__ __launch_bounds__(256) void convert_tables(
    const float* __restrict__ ue, const float* __restrict__ ee,
    ushort* __restrict__ ueh, ushort* __restrict__ eeh)
{
    int i4 = blockIdx.x * 256 + threadIdx.x;   // float4 units
    if (i4 < 128000) {
        float4 v = ((const float4*)ue)[i4];
        ushort4 o; o.x = f2bf(v.x); o.y = f2bf(v.y); o.z = f2bf(v.z); o.w = f2bf(v.w);
        ((ushort4*)ueh)[i4] = o;
    } else if (i4 < 640000) {
        int j = i4 - 128000;
        float4 v = ((const float4*)ee)[j];
        ushort4 o; o.x = f2bf(v.x); o.y = f2bf(v.y); o.z = f2bf(v.z); o.w = f2bf(v.w);
        ((ushort4*)eeh)[j] = o;
    }
}

// ---------------------------------------------------------------------------
// Linked-list adjacency build. pack[e] = {prev_head (next ptr), other endpoint}
// All writes coalesced; atomics on small L2-resident head tables only.
// ---------------------------------------------------------------------------
__global__ __launch_bounds__(256) void build_links(
    const int* __restrict__ ui_index, const int* __restrict__ ei_index,
    int* __restrict__ head_u, int* __restrict__ head_e,
    int2* __restrict__ pack_u, int2* __restrict__ pack_e)
{
    int g = blockIdx.y;
    const int* ui = ui_index + (size_t)g * N_EDGES;
    const int* ei = ei_index + (size_t)g * N_EDGES;
    int* hu = head_u + (size_t)g * HEADU_STRIDE;
    int* he = head_e + (size_t)g * HEADE_STRIDE;
    int2* pu = pack_u + (size_t)g * N_EDGES;
    int2* pe = pack_e + (size_t)g * N_EDGES;
    int e = blockIdx.x * 256 + threadIdx.x;
    if (e >= N_EDGES) return;
    int u = ui[e], v = ei[e];
    int p = atomicExch(&hu[(u << 2) | (e & 3)], e);
    pu[e] = make_int2(p, v);
    int q = atomicExch(&he[(v << 2) | (e & 3)], e);
    pe[e] = make_int2(q, u);
}

// ---------------------------------------------------------------------------
// Walk 4 parity chains of one row, summing bf16 table rows. Lane = dim.
// ---------------------------------------------------------------------------
__device__ __forceinline__ float walk_sum(
    const int* __restrict__ head4, const int2* __restrict__ pack,
    const ushort* __restrict__ table, int row, int lane)
{
    int e0 = head4[row * 4 + 0], e1 = head4[row * 4 + 1];
    int e2 = head4[row * 4 + 2], e3 = head4[row * 4 + 3];
    float s0 = 0.f, s1 = 0.f, s2 = 0.f, s3 = 0.f;
    while ((e0 & e1 & e2 & e3) >= 0) {   // while ANY chain active
        if (e0 >= 0) { int2 p = pack[e0]; s0 += bf2f(table[(p.y << 6) + lane]); e0 = p.x; }
        if (e1 >= 0) { int2 p = pack[e1]; s1 += bf2f(table[(p.y << 6) + lane]); e1 = p.x; }
        if (e2 >= 0) { int2 p = pack[e2]; s2 += bf2f(table[(p.y << 6) + lane]); e2 = p.x; }
        if (e3 >= 0) { int2 p = pack[e3]; s3 += bf2f(table[(p.y << 6) + lane]); e3 = p.x; }
    }
    return (s0 + s1) + (s2 + s3);
}

__device__ __forceinline__ float l2n(float v) {
    float ss = v * v;
    #pragma unroll
    for (int off = 1; off < 64; off <<= 1) ss += __shfl_xor(ss, off);
    return v / fmaxf(sqrtf(ss), 1e-12f);
}

// ---------------------------------------------------------------------------
// hop0: blocks [0, 8000) entity side (ebufh = bf16 norm(sum ueh));
//       blocks [8000, 10000) user side (acc[g] = norm(sum eeh)).
// ---------------------------------------------------------------------------
__global__ __launch_bounds__(256) void agg_hop0(
    const int* __restrict__ head_u, const int* __restrict__ head_e,
    const int2* __restrict__ pack_u, const int2* __restrict__ pack_e,
    const ushort* __restrict__ ueh, const ushort* __restrict__ eeh,
    ushort* __restrict__ ebufh, float* __restrict__ acc, int gbase)
{
    int gz = blockIdx.z;
    int g = gbase + gz;
    int w = threadIdx.x >> 6, lane = threadIdx.x & 63;
    int rb = blockIdx.x;
    if (rb < N_ENTITIES / 4) {
        int row = rb * 4 + w;
        float v = walk_sum(head_e + (size_t)g * HEADE_STRIDE,
                           pack_e + (size_t)g * N_EDGES, ueh, row, lane);
        ebufh[(size_t)gz * N_ENTITIES * EMB + (row << 6) + lane] = f2bf(l2n(v));
    } else {
        int row = (rb - N_ENTITIES / 4) * 4 + w;
        float v = walk_sum(head_u + (size_t)g * HEADU_STRIDE,
                           pack_u + (size_t)g * N_EDGES, eeh, row, lane);
        acc[(size_t)g * N_USERS * EMB + (row << 6) + lane] = l2n(v);
    }
}

// ---------------------------------------------------------------------------
// hop1 user side: acc[g] += norm(sum ebufh[gz][ei])
// ---------------------------------------------------------------------------
__global__ __launch_bounds__(256) void agg_hop1(
    const int* __restrict__ head_u, const int2* __restrict__ pack_u,
    const ushort* __restrict__ ebufh, float* __restrict__ acc, int gbase)
{
    int gz = blockIdx.z;
    int g = gbase + gz;
    int row = blockIdx.x * 4 + (threadIdx.x >> 6);
    int lane = threadIdx.x & 63;
    float v = walk_sum(head_u + (size_t)g * HEADU_STRIDE,
                       pack_u + (size_t)g * N_EDGES,
                       ebufh + (size_t)gz * N_ENTITIES * EMB, row, lane);
    acc[(size_t)g * N_USERS * EMB + (row << 6) + lane] += l2n(v);
}

// ---------------------------------------------------------------------------
// Fused: attention-combine -> out_user; proj+normalize of (uie, out_user)
// -> p1/p2 (+bf16 copies); diag = 2*dot(p1,p2).
// ---------------------------------------------------------------------------
__global__ __launch_bounds__(256) void combine_proj(
    const float* __restrict__ acc, const float* __restrict__ uie,
    const float* __restrict__ uemb,
    const float* __restrict__ W1, const float* __restrict__ b1,
    const float* __restrict__ W2, const float* __restrict__ b2,
    float* __restrict__ out_user,
    float* __restrict__ p1, float* __restrict__ p2,
    ushort* __restrict__ p1h, ushort* __restrict__ p2h,
    float* __restrict__ diag)
{
    __shared__ float W1s[EMB * EMB];
    __shared__ float W2s[EMB * EMB];
    __shared__ float zs[4][2][EMB];
    __shared__ float hs[4][2][EMB];
    int t = threadIdx.x;
    for (int i = t; i < EMB * EMB; i += 256) { W1s[i] = W1[i]; W2s[i] = W2[i]; }
    int w = t >> 6, lane = t & 63;
    int u = blockIdx.x * 4 + w;

    float ue = uie[(u << 6) + lane];
    float av[N_GROUPS], s[N_GROUPS];
    #pragma unroll
    for (int g = 0; g < N_GROUPS; ++g) {
        av[g] = acc[(size_t)g * N_USERS * EMB + (u << 6) + lane];
        float p = av[g] * ue;
        #pragma unroll
        for (int off = 1; off < 64; off <<= 1) p += __shfl_xor(p, off);
        s[g] = p;
    }
    float m = fmaxf(fmaxf(s[0], s[1]), fmaxf(s[2], s[3]));
    float att[N_GROUPS], tot = 0.f;
    #pragma unroll
    for (int g = 0; g < N_GROUPS; ++g) { att[g] = __expf(s[g] - m); tot += att[g]; }
    float inv = 1.0f / tot;
    float o = uemb[(u << 6) + lane];
    #pragma unroll
    for (int g = 0; g < N_GROUPS; ++g) o += att[g] * inv * av[g];
    out_user[(u << 6) + lane] = o;

    zs[w][0][lane] = ue;
    zs[w][1][lane] = o;
    __syncthreads();
    float h0 = b1[lane], h1 = b1[lane];
    #pragma unroll
    for (int k = 0; k < EMB; ++k) {
        float w1 = W1s[k * EMB + lane];
        h0 = fmaf(zs[w][0][k], w1, h0);
        h1 = fmaf(zs[w][1][k], w1, h1);
    }
    h0 = h0 > 0.f ? h0 : expm1f(h0);
    h1 = h1 > 0.f ? h1 : expm1f(h1);
    hs[w][0][lane] = h0;
    hs[w][1][lane] = h1;
    __syncthreads();
    float y0 = b2[lane], y1 = b2[lane];
    #pragma unroll
    for (int k = 0; k < EMB; ++k) {
        float w2 = W2s[k * EMB + lane];
        y0 = fmaf(hs[w][0][k], w2, y0);
        y1 = fmaf(hs[w][1][k], w2, y1);
    }
    float ss0 = y0 * y0, ss1 = y1 * y1;
    #pragma unroll
    for (int off = 1; off < 64; off <<= 1) {
        ss0 += __shfl_xor(ss0, off);
        ss1 += __shfl_xor(ss1, off);
    }
    float n0 = y0 / fmaxf(sqrtf(ss0), 1e-12f);
    float n1 = y1 / fmaxf(sqrtf(ss1), 1e-12f);
    p1[(u << 6) + lane] = n0;
    p2[(u << 6) + lane] = n1;
    p1h[(u << 6) + lane] = f2bf(n0);
    p2h[(u << 6) + lane] = f2bf(n1);
    float d = n0 * n1;
    #pragma unroll
    for (int off = 1; off < 64; off <<= 1) d += __shfl_xor(d, off);
    if (lane == 0) diag[u] = d * 2.0f;
}

// ---------------------------------------------------------------------------
// MFMA LSE: one traversal of logits = 2 * A@B^T -> row & col exp-sum partials.
// ---------------------------------------------------------------------------
#define NCHUNK 25
#define TILES_PER_CHUNK 10
#define NWAVES (250 * NCHUNK)
__global__ __launch_bounds__(256) void lse_mfma(
    const ushort* __restrict__ Ah, const ushort* __restrict__ Bh,
    float* __restrict__ rowp, float* __restrict__ colp)
{
    int W = blockIdx.x * 4 + (threadIdx.x >> 6);
    if (W >= NWAVES) return;
    int lane = threadIdx.x & 63;
    int strip = W / NCHUNK;
    int chunk = W % NCHUNK;
    int i0 = strip * 32;
    int hl = lane >> 5;
    int l31 = lane & 31;

    const bf16x8* A8 = (const bf16x8*)Ah;
    const bf16x8* B8 = (const bf16x8*)Bh;

    bf16x8 afrag[4];
    #pragma unroll
    for (int m = 0; m < 4; ++m)
        afrag[m] = A8[(i0 + l31) * 8 + m * 2 + hl];

    float rowacc[16];
    #pragma unroll
    for (int r = 0; r < 16; ++r) rowacc[r] = 0.f;

    for (int tj = 0; tj < TILES_PER_CHUNK; ++tj) {
        int j0 = chunk * (TILES_PER_CHUNK * 32) + tj * 32;
        bf16x8 bfrag[4];
        #pragma unroll
        for (int m = 0; m < 4; ++m)
            bfrag[m] = B8[(j0 + l31) * 8 + m * 2 + hl];
        f32x16 acc;
        #pragma unroll
        for (int r = 0; r < 16; ++r) acc[r] = 0.f;
        #pragma unroll
        for (int m = 0; m < 4; ++m)
            acc = __builtin_amdgcn_mfma_f32_32x32x16_bf16(afrag[m], bfrag[m], acc, 0, 0, 0);
        float csum = 0.f;
        #pragma unroll
        for (int r = 0; r < 16; ++r) {
            float e = __expf(acc[r] * 2.0f);
            rowacc[r] += e;
            csum += e;
        }
        csum += __shfl_xor(csum, 32);
        if (lane < 32) colp[strip * 8000 + j0 + lane] = csum;
    }
    #pragma unroll
    for (int r = 0; r < 16; ++r) {
        float v = rowacc[r];
        #pragma unroll
        for (int off = 1; off < 32; off <<= 1) v += __shfl_xor(v, off);
        if (l31 == 0)
            rowp[chunk * 8000 + i0 + (r & 3) + 8 * (r >> 2) + 4 * hl] = v;
    }
}

// ---------------------------------------------------------------------------
// se_row[i] = sum_c rowp[c][i]; se_col[j] = sum_s colp[s][j]
// ---------------------------------------------------------------------------
__global__ __launch_bounds__(256) void reduce_partials(
    const float* __restrict__ rowp, const float* __restrict__ colp,
    float* __restrict__ se_row, float* __restrict__ se_col)
{
    int id = blockIdx.x * 256 + threadIdx.x;
    if (id < N_USERS) {
        float s = 0.f;
        for (int c = 0; c < NCHUNK; ++c) s += rowp[c * 8000 + id];
        se_row[id] = s;
    } else if (id < 2 * N_USERS) {
        int j = id - N_USERS;
        float s = 0.f;
        for (int st = 0; st < 250; ++st) s += colp[st * 8000 + j];
        se_col[j] = s;
    }
}

// ---------------------------------------------------------------------------
// loss = mean_i( 0.5*(log(se_row)+log(se_col)) - diag )
// ---------------------------------------------------------------------------
__global__ __launch_bounds__(256) void loss_kernel(
    const float* __restrict__ se_row, const float* __restrict__ se_col,
    const float* __restrict__ diag, float* __restrict__ out)
{
    __shared__ float red[256];
    int t = threadIdx.x;
    float s = 0.f;
    for (int i = t; i < N_USERS; i += 256)
        s += 0.5f * (logf(se_row[i]) + logf(se_col[i])) - diag[i];
    red[t] = s;
    __syncthreads();
    for (int w = 128; w > 0; w >>= 1) {
        if (t < w) red[t] += red[t + w];
        __syncthreads();
    }
    if (t == 0) out[0] = red[0] / (float)N_USERS;
}

extern "C" void kernel_launch(void* const* d_in, const int* in_sizes, int n_in,
                              void* d_out, int out_size, void* d_ws, size_t ws_size,
                              hipStream_t stream)
{
    const float* user_emb   = (const float*)d_in[0];
    const float* user_ui    = (const float*)d_in[1];
    const float* entity_emb = (const float*)d_in[2];
    const float* W1 = (const float*)d_in[3];
    const float* b1 = (const float*)d_in[4];
    const float* W2 = (const float*)d_in[5];
    const float* b2 = (const float*)d_in[6];
    const int* ui_index = (const int*)d_in[7];
    const int* ei_index = (const int*)d_in[8];

    float* ws = (float*)d_ws;
    // Layout (float units). Lifetimes are stream-ordered; overlays noted.
    float* acc    = ws;                        // [0, 2,048,000)  dead after combine_proj
    float* colp   = acc;                       //   overlay: lse_mfma col partials (2,000,000)
    float* se_row = ws + 2048000;              // 8,000
    float* se_col = se_row + 8000;             // 8,000
    float* diag   = se_col + 8000;             // 8,000   (ends 2,072,000)
    int* head_u = (int*)(ws + 2072000);        // 4*32768
    int* head_e = head_u + 4 * HEADU_STRIDE;   // 4*131072 (ends 2,727,360)
    int2* pack_u = (int2*)(ws + 2727360);      // 4*200000 int2  dead after agg_hop1
    float* rowp = (float*)pack_u;              //   overlay: lse row partials (200,000)
    int2* pack_e = pack_u + 4 * N_EDGES;       // 4*200000 int2 (ends 5,927,360) dead after agg_hop0
    float* p1 = (float*)pack_e;                //   overlay: 512,000
    float* p2 = p1 + 512000;                   //   512,000
    ushort* p1h = (ushort*)(p2 + 512000);      //   512,000 ushort
    ushort* p2h = p1h + 512000;                //   512,000 ushort (1,536,000 f-units <= pack_e's 1,600,000)
    ushort* ueh = (ushort*)(ws + 5927360);     // 512,000 ushort (256,000 f)
    ushort* eeh = (ushort*)(ws + 6183360);     // 2,048,000 ushort (1,024,000 f)
    ushort* ebufh = (ushort*)(ws + 7207360);   // nG * 2,048,000 ushort

    const size_t FUSED_BYTES = (size_t)(7207360 + 4 * 1024000) * 4;   // 45.2 MB
    int nG = (ws_size >= FUSED_BYTES) ? N_GROUPS : 1;

    float* out_user = (float*)d_out;           // 512,000
    float* out_loss = out_user + 512000;       // 1

    dim3 b256(256);

    hipMemsetAsync(head_u, 0xFF,
                   (size_t)(4 * HEADU_STRIDE + 4 * HEADE_STRIDE) * 4, stream);
    convert_tables<<<2500, b256, 0, stream>>>(user_emb, entity_emb, ueh, eeh);
    build_links<<<dim3((N_EDGES + 255) / 256, N_GROUPS), b256, 0, stream>>>(
        ui_index, ei_index, head_u, head_e, pack_u, pack_e);

    for (int gbase = 0; gbase < N_GROUPS; gbase += nG) {
        agg_hop0<<<dim3(N_ENTITIES / 4 + N_USERS / 4, 1, nG), b256, 0, stream>>>(
            head_u, head_e, pack_u, pack_e, ueh, eeh, ebufh, acc, gbase);
        agg_hop1<<<dim3(N_USERS / 4, 1, nG), b256, 0, stream>>>(
            head_u, pack_u, ebufh, acc, gbase);
    }

    combine_proj<<<N_USERS / 4, b256, 0, stream>>>(
        acc, user_ui, user_emb, W1, b1, W2, b2,
        out_user, p1, p2, p1h, p2h, diag);

    lse_mfma<<<(NWAVES + 3) / 4, b256, 0, stream>>>(p1h, p2h, rowp, colp);
    reduce_partials<<<(2 * N_USERS + 255) / 256, b256, 0, stream>>>(
        rowp, colp, se_row, se_col);
    loss_kernel<<<1, b256, 0, stream>>>(se_row, se_col, diag, out_loss);
}

// Round 6
// 375.924 us; speedup vs baseline: 4.0233x; 1.0901x over previous
//
#include <hip/hip_runtime.h>
#include <hip/hip_bf16.h>
#include <math.h>

#define N_USERS 8000
#define N_ENTITIES 32000
#define EMB 64
#define N_GROUPS 4
#define N_EDGES 200000

#define NPAR_U 16                      // parity chains per user row
#define NPAR_E 8                       // parity chains per entity row
#define HU_STRIDE (N_USERS * NPAR_U)   // 128,000 ints per group
#define HE_STRIDE (N_ENTITIES * NPAR_E)// 256,000 ints per group

typedef __attribute__((ext_vector_type(8))) __bf16 bf16x8;
typedef __attribute__((ext_vector_type(16))) float f32x16;

static __device__ __forceinline__ float bf2f(unsigned short u) {
    union { unsigned int i; float f; } x; x.i = ((unsigned int)u) << 16; return x.f;
}
static __device__ __forceinline__ unsigned short f2bf(float f) {
    union { float f; unsigned int i; } x; x.f = f;
    return (unsigned short)((x.i + 0x7FFF + ((x.i >> 16) & 1)) >> 16);
}

// ---------------------------------------------------------------------------
// Convert user_emb / entity_emb to bf16 tables.
// ---------------------------------------------------------------------------
__global__ __launch_bounds__(256) void convert_tables(
    const float* __restrict__ ue, const float* __restrict__ ee,
    ushort* __restrict__ ueh, ushort* __restrict__ eeh)
{
    int i4 = blockIdx.x * 256 + threadIdx.x;   // float4 units
    if (i4 < 128000) {
        float4 v = ((const float4*)ue)[i4];
        ushort4 o; o.x = f2bf(v.x); o.y = f2bf(v.y); o.z = f2bf(v.z); o.w = f2bf(v.w);
        ((ushort4*)ueh)[i4] = o;
    } else if (i4 < 640000) {
        int j = i4 - 128000;
        float4 v = ((const float4*)ee)[j];
        ushort4 o; o.x = f2bf(v.x); o.y = f2bf(v.y); o.z = f2bf(v.z); o.w = f2bf(v.w);
        ((ushort4*)eeh)[j] = o;
    }
}

// ---------------------------------------------------------------------------
// Linked-list adjacency build, NPAR parity chains per row.
// pack[e] = {next ptr, other endpoint}; writes coalesced.
// ---------------------------------------------------------------------------
__global__ __launch_bounds__(256) void build_links(
    const int* __restrict__ ui_index, const int* __restrict__ ei_index,
    int* __restrict__ head_u, int* __restrict__ head_e,
    int2* __restrict__ pack_u, int2* __restrict__ pack_e)
{
    int g = blockIdx.y;
    const int* ui = ui_index + (size_t)g * N_EDGES;
    const int* ei = ei_index + (size_t)g * N_EDGES;
    int* hu = head_u + (size_t)g * HU_STRIDE;
    int* he = head_e + (size_t)g * HE_STRIDE;
    int2* pu = pack_u + (size_t)g * N_EDGES;
    int2* pe = pack_e + (size_t)g * N_EDGES;
    int e = blockIdx.x * 256 + threadIdx.x;
    if (e >= N_EDGES) return;
    int u = ui[e], v = ei[e];
    int p = atomicExch(&hu[(u * NPAR_U) | (e & (NPAR_U - 1))], e);
    pu[e] = make_int2(p, v);
    int q = atomicExch(&he[(v * NPAR_E) | (e & (NPAR_E - 1))], e);
    pe[e] = make_int2(q, u);
}

// ---------------------------------------------------------------------------
// Lane-parallel chain walk: lane c < NPAR holds chain c's cursor. Each step:
// one per-lane pack load (NPAR concurrent chases), then readlane-broadcast
// sources feed scalar-based coalesced row gathers by all 64 lanes.
// ---------------------------------------------------------------------------
template<int NPAR>
__device__ __forceinline__ float walkN(
    const int* __restrict__ head, const int2* __restrict__ pack,
    const ushort* __restrict__ table, int row, int lane)
{
    int e = (lane < NPAR) ? head[row * NPAR + lane] : -1;
    float s0 = 0.f, s1 = 0.f;
    while (__any(e >= 0)) {
        int2 p = pack[e >= 0 ? e : 0];
        int srcb = (e >= 0) ? p.y : -1;
        #pragma unroll
        for (int c = 0; c < NPAR; ++c) {
            int sc = __shfl(srcb, c);          // literal lane -> v_readlane (SGPR)
            if (sc >= 0) {
                float v = bf2f(table[(sc << 6) + lane]);
                if (c & 1) s1 += v; else s0 += v;
            }
        }
        e = (e >= 0) ? p.x : e;
    }
    return s0 + s1;
}

__device__ __forceinline__ float l2n(float v) {
    float ss = v * v;
    #pragma unroll
    for (int off = 1; off < 64; off <<= 1) ss += __shfl_xor(ss, off);
    return v / fmaxf(sqrtf(ss), 1e-12f);
}

// ---------------------------------------------------------------------------
// hop0: blocks [0, 8000) entity side (ebufh = bf16 norm(sum ueh));
//       blocks [8000, 10000) user side (acc[g] = norm(sum eeh)).
// ---------------------------------------------------------------------------
__global__ __launch_bounds__(256) void agg_hop0(
    const int* __restrict__ head_u, const int* __restrict__ head_e,
    const int2* __restrict__ pack_u, const int2* __restrict__ pack_e,
    const ushort* __restrict__ ueh, const ushort* __restrict__ eeh,
    ushort* __restrict__ ebufh, float* __restrict__ acc, int gbase)
{
    int gz = blockIdx.z;
    int g = gbase + gz;
    int w = threadIdx.x >> 6, lane = threadIdx.x & 63;
    int rb = blockIdx.x;
    if (rb < N_ENTITIES / 4) {
        int row = rb * 4 + w;
        float v = walkN<NPAR_E>(head_e + (size_t)g * HE_STRIDE,
                                pack_e + (size_t)g * N_EDGES, ueh, row, lane);
        ebufh[(size_t)gz * N_ENTITIES * EMB + (row << 6) + lane] = f2bf(l2n(v));
    } else {
        int row = (rb - N_ENTITIES / 4) * 4 + w;
        float v = walkN<NPAR_U>(head_u + (size_t)g * HU_STRIDE,
                                pack_u + (size_t)g * N_EDGES, eeh, row, lane);
        acc[(size_t)g * N_USERS * EMB + (row << 6) + lane] = l2n(v);
    }
}

// ---------------------------------------------------------------------------
// hop1 user side: acc[g] += norm(sum ebufh[gz][ei])
// ---------------------------------------------------------------------------
__global__ __launch_bounds__(256) void agg_hop1(
    const int* __restrict__ head_u, const int2* __restrict__ pack_u,
    const ushort* __restrict__ ebufh, float* __restrict__ acc, int gbase)
{
    int gz = blockIdx.z;
    int g = gbase + gz;
    int row = blockIdx.x * 4 + (threadIdx.x >> 6);
    int lane = threadIdx.x & 63;
    float v = walkN<NPAR_U>(head_u + (size_t)g * HU_STRIDE,
                            pack_u + (size_t)g * N_EDGES,
                            ebufh + (size_t)gz * N_ENTITIES * EMB, row, lane);
    acc[(size_t)g * N_USERS * EMB + (row << 6) + lane] += l2n(v);
}

// ---------------------------------------------------------------------------
// Fused: attention-combine -> out_user; proj+normalize of (uie, out_user)
// -> bf16 p1h/p2h; diag = 2*dot(n0,n1).
// ---------------------------------------------------------------------------
__global__ __launch_bounds__(256) void combine_proj(
    const float* __restrict__ acc, const float* __restrict__ uie,
    const float* __restrict__ uemb,
    const float* __restrict__ W1, const float* __restrict__ b1,
    const float* __restrict__ W2, const float* __restrict__ b2,
    float* __restrict__ out_user,
    ushort* __restrict__ p1h, ushort* __restrict__ p2h,
    float* __restrict__ diag)
{
    __shared__ float W1s[EMB * EMB];
    __shared__ float W2s[EMB * EMB];
    __shared__ float zs[4][2][EMB];
    __shared__ float hs[4][2][EMB];
    int t = threadIdx.x;
    for (int i = t; i < EMB * EMB; i += 256) { W1s[i] = W1[i]; W2s[i] = W2[i]; }
    int w = t >> 6, lane = t & 63;
    int u = blockIdx.x * 4 + w;

    float ue = uie[(u << 6) + lane];
    float av[N_GROUPS], s[N_GROUPS];
    #pragma unroll
    for (int g = 0; g < N_GROUPS; ++g) {
        av[g] = acc[(size_t)g * N_USERS * EMB + (u << 6) + lane];
        float p = av[g] * ue;
        #pragma unroll
        for (int off = 1; off < 64; off <<= 1) p += __shfl_xor(p, off);
        s[g] = p;
    }
    float m = fmaxf(fmaxf(s[0], s[1]), fmaxf(s[2], s[3]));
    float att[N_GROUPS], tot = 0.f;
    #pragma unroll
    for (int g = 0; g < N_GROUPS; ++g) { att[g] = __expf(s[g] - m); tot += att[g]; }
    float inv = 1.0f / tot;
    float o = uemb[(u << 6) + lane];
    #pragma unroll
    for (int g = 0; g < N_GROUPS; ++g) o += att[g] * inv * av[g];
    out_user[(u << 6) + lane] = o;

    zs[w][0][lane] = ue;
    zs[w][1][lane] = o;
    __syncthreads();
    float h0 = b1[lane], h1 = b1[lane];
    #pragma unroll
    for (int k = 0; k < EMB; ++k) {
        float w1 = W1s[k * EMB + lane];
        h0 = fmaf(zs[w][0][k], w1, h0);
        h1 = fmaf(zs[w][1][k], w1, h1);
    }
    h0 = h0 > 0.f ? h0 : expm1f(h0);
    h1 = h1 > 0.f ? h1 : expm1f(h1);
    hs[w][0][lane] = h0;
    hs[w][1][lane] = h1;
    __syncthreads();
    float y0 = b2[lane], y1 = b2[lane];
    #pragma unroll
    for (int k = 0; k < EMB; ++k) {
        float w2 = W2s[k * EMB + lane];
        y0 = fmaf(hs[w][0][k], w2, y0);
        y1 = fmaf(hs[w][1][k], w2, y1);
    }
    float ss0 = y0 * y0, ss1 = y1 * y1;
    #pragma unroll
    for (int off = 1; off < 64; off <<= 1) {
        ss0 += __shfl_xor(ss0, off);
        ss1 += __shfl_xor(ss1, off);
    }
    float n0 = y0 / fmaxf(sqrtf(ss0), 1e-12f);
    float n1 = y1 / fmaxf(sqrtf(ss1), 1e-12f);
    p1h[(u << 6) + lane] = f2bf(n0);
    p2h[(u << 6) + lane] = f2bf(n1);
    float d = n0 * n1;
    #pragma unroll
    for (int off = 1; off < 64; off <<= 1) d += __shfl_xor(d, off);
    if (lane == 0) diag[u] = d * 2.0f;
}

// ---------------------------------------------------------------------------
// MFMA LSE: one traversal of logits = 2 * A@B^T -> row & col exp-sum partials.
// ---------------------------------------------------------------------------
#define NCHUNK 25
#define TILES_PER_CHUNK 10
#define NWAVES (250 * NCHUNK)
__global__ __launch_bounds__(256) void lse_mfma(
    const ushort* __restrict__ Ah, const ushort* __restrict__ Bh,
    float* __restrict__ rowp, float* __restrict__ colp)
{
    int W = blockIdx.x * 4 + (threadIdx.x >> 6);
    if (W >= NWAVES) return;
    int lane = threadIdx.x & 63;
    int strip = W / NCHUNK;
    int chunk = W % NCHUNK;
    int i0 = strip * 32;
    int hl = lane >> 5;
    int l31 = lane & 31;

    const bf16x8* A8 = (const bf16x8*)Ah;
    const bf16x8* B8 = (const bf16x8*)Bh;

    bf16x8 afrag[4];
    #pragma unroll
    for (int m = 0; m < 4; ++m)
        afrag[m] = A8[(i0 + l31) * 8 + m * 2 + hl];

    float rowacc[16];
    #pragma unroll
    for (int r = 0; r < 16; ++r) rowacc[r] = 0.f;

    for (int tj = 0; tj < TILES_PER_CHUNK; ++tj) {
        int j0 = chunk * (TILES_PER_CHUNK * 32) + tj * 32;
        bf16x8 bfrag[4];
        #pragma unroll
        for (int m = 0; m < 4; ++m)
            bfrag[m] = B8[(j0 + l31) * 8 + m * 2 + hl];
        f32x16 acc;
        #pragma unroll
        for (int r = 0; r < 16; ++r) acc[r] = 0.f;
        #pragma unroll
        for (int m = 0; m < 4; ++m)
            acc = __builtin_amdgcn_mfma_f32_32x32x16_bf16(afrag[m], bfrag[m], acc, 0, 0, 0);
        float csum = 0.f;
        #pragma unroll
        for (int r = 0; r < 16; ++r) {
            float e = __expf(acc[r] * 2.0f);
            rowacc[r] += e;
            csum += e;
        }
        csum += __shfl_xor(csum, 32);
        if (lane < 32) colp[strip * 8000 + j0 + lane] = csum;
    }
    #pragma unroll
    for (int r = 0; r < 16; ++r) {
        float v = rowacc[r];
        #pragma unroll
        for (int off = 1; off < 32; off <<= 1) v += __shfl_xor(v, off);
        if (l31 == 0)
            rowp[chunk * 8000 + i0 + (r & 3) + 8 * (r >> 2) + 4 * hl] = v;
    }
}

// ---------------------------------------------------------------------------
// se_row[i] = sum_c rowp[c][i]; se_col[j] = sum_s colp[s][j]
// ---------------------------------------------------------------------------
__global__ __launch_bounds__(256) void reduce_partials(
    const float* __restrict__ rowp, const float* __restrict__ colp,
    float* __restrict__ se_row, float* __restrict__ se_col)
{
    int id = blockIdx.x * 256 + threadIdx.x;
    if (id < N_USERS) {
        float s = 0.f;
        for (int c = 0; c < NCHUNK; ++c) s += rowp[c * 8000 + id];
        se_row[id] = s;
    } else if (id < 2 * N_USERS) {
        int j = id - N_USERS;
        float s = 0.f;
        for (int st = 0; st < 250; ++st) s += colp[st * 8000 + j];
        se_col[j] = s;
    }
}

// ---------------------------------------------------------------------------
// loss = mean_i( 0.5*(log(se_row)+log(se_col)) - diag )
// ---------------------------------------------------------------------------
__global__ __launch_bounds__(256) void loss_kernel(
    const float* __restrict__ se_row, const float* __restrict__ se_col,
    const float* __restrict__ diag, float* __restrict__ out)
{
    __shared__ float red[256];
    int t = threadIdx.x;
    float s = 0.f;
    for (int i = t; i < N_USERS; i += 256)
        s += 0.5f * (logf(se_row[i]) + logf(se_col[i])) - diag[i];
    red[t] = s;
    __syncthreads();
    for (int w = 128; w > 0; w >>= 1) {
        if (t < w) red[t] += red[t + w];
        __syncthreads();
    }
    if (t == 0) out[0] = red[0] / (float)N_USERS;
}

extern "C" void kernel_launch(void* const* d_in, const int* in_sizes, int n_in,
                              void* d_out, int out_size, void* d_ws, size_t ws_size,
                              hipStream_t stream)
{
    const float* user_emb   = (const float*)d_in[0];
    const float* user_ui    = (const float*)d_in[1];
    const float* entity_emb = (const float*)d_in[2];
    const float* W1 = (const float*)d_in[3];
    const float* b1 = (const float*)d_in[4];
    const float* W2 = (const float*)d_in[5];
    const float* b2 = (const float*)d_in[6];
    const int* ui_index = (const int*)d_in[7];
    const int* ei_index = (const int*)d_in[8];

    float* ws = (float*)d_ws;
    // Layout (float units). Lifetimes stream-ordered; overlays noted.
    float* acc    = ws;                        // [0, 2,048,000) dead after combine_proj
    float* colp   = acc;                       //   overlay: lse col partials (2,000,000)
    float* se_row = ws + 2048000;              // 8,000
    float* se_col = se_row + 8000;             // 8,000
    float* diag   = se_col + 8000;             // 8,000  (ends 2,072,000)
    int* head_u = (int*)(ws + 2072000);        // 4*128,000 = 512,000 ints
    int* head_e = head_u + 4 * HU_STRIDE;      // 4*256,000 = 1,024,000 ints (ends 3,608,000)
    int2* pack_u = (int2*)(ws + 3608000);      // 4*200,000 int2 (1,600,000 f) dead after hop1
    float* rowp = (float*)pack_u;              //   overlay: lse row partials (200,000)
    int2* pack_e = pack_u + 4 * N_EDGES;       // 4*200,000 int2 (ends 6,808,000) dead after hop0
    ushort* p1h = (ushort*)pack_e;             //   overlay: 512,000 ushort
    ushort* p2h = p1h + 512000;                //   512,000 ushort (512,000 f <= 1,600,000 f)
    ushort* ueh = (ushort*)(ws + 6808000);     // 512,000 ushort (256,000 f)
    ushort* eeh = (ushort*)(ws + 7064000);     // 2,048,000 ushort (1,024,000 f; ends 8,088,000)
    ushort* ebufh = (ushort*)(ws + 8088000);   // nG * 2,048,000 ushort

    const size_t BASE_F = 8088000;
    int nG = 1;
    if (ws_size >= (BASE_F + 4 * 1024000) * 4) nG = 4;       // 48.7 MB
    else if (ws_size >= (BASE_F + 2 * 1024000) * 4) nG = 2;  // 40.5 MB

    float* out_user = (float*)d_out;           // 512,000
    float* out_loss = out_user + 512000;       // 1

    dim3 b256(256);

    hipMemsetAsync(head_u, 0xFF,
                   (size_t)(4 * HU_STRIDE + 4 * HE_STRIDE) * 4, stream);
    convert_tables<<<2500, b256, 0, stream>>>(user_emb, entity_emb, ueh, eeh);
    build_links<<<dim3((N_EDGES + 255) / 256, N_GROUPS), b256, 0, stream>>>(
        ui_index, ei_index, head_u, head_e, pack_u, pack_e);

    for (int gbase = 0; gbase < N_GROUPS; gbase += nG) {
        agg_hop0<<<dim3(N_ENTITIES / 4 + N_USERS / 4, 1, nG), b256, 0, stream>>>(
            head_u, head_e, pack_u, pack_e, ueh, eeh, ebufh, acc, gbase);
        agg_hop1<<<dim3(N_USERS / 4, 1, nG), b256, 0, stream>>>(
            head_u, pack_u, ebufh, acc, gbase);
    }

    combine_proj<<<N_USERS / 4, b256, 0, stream>>>(
        acc, user_ui, user_emb, W1, b1, W2, b2,
        out_user, p1h, p2h, diag);

    lse_mfma<<<(NWAVES + 3) / 4, b256, 0, stream>>>(p1h, p2h, rowp, colp);
    reduce_partials<<<(2 * N_USERS + 255) / 256, b256, 0, stream>>>(
        rowp, colp, se_row, se_col);
    loss_kernel<<<1, b256, 0, stream>>>(se_row, se_col, diag, out_loss);
}

// Round 7
// 306.223 us; speedup vs baseline: 4.9390x; 1.2276x over previous
//
#include <hip/hip_runtime.h>
#include <hip/hip_bf16.h>
#include <math.h>

#define N_USERS 8000
#define N_ENTITIES 32000
#define EMB 64
#define N_GROUPS 4
#define N_EDGES 200000

#define NPAR_U 16                      // parity chains per user row
#define NPAR_E 8                       // parity chains per entity row
#define HU_STRIDE (N_USERS * NPAR_U)   // 128,000 ints per group
#define HE_STRIDE (N_ENTITIES * NPAR_E)// 256,000 ints per group

typedef __attribute__((ext_vector_type(8))) __bf16 bf16x8;
typedef __attribute__((ext_vector_type(16))) float f32x16;

static __device__ __forceinline__ float bf2f(unsigned short u) {
    union { unsigned int i; float f; } x; x.i = ((unsigned int)u) << 16; return x.f;
}
static __device__ __forceinline__ unsigned short f2bf(float f) {
    union { float f; unsigned int i; } x; x.f = f;
    return (unsigned short)((x.i + 0x7FFF + ((x.i >> 16) & 1)) >> 16);
}

// ---------------------------------------------------------------------------
// Convert user_emb / entity_emb to bf16 tables.
// ---------------------------------------------------------------------------
__global__ __launch_bounds__(256) void convert_tables(
    const float* __restrict__ ue, const float* __restrict__ ee,
    ushort* __restrict__ ueh, ushort* __restrict__ eeh)
{
    int i4 = blockIdx.x * 256 + threadIdx.x;   // float4 units
    if (i4 < 128000) {
        float4 v = ((const float4*)ue)[i4];
        ushort4 o; o.x = f2bf(v.x); o.y = f2bf(v.y); o.z = f2bf(v.z); o.w = f2bf(v.w);
        ((ushort4*)ueh)[i4] = o;
    } else if (i4 < 640000) {
        int j = i4 - 128000;
        float4 v = ((const float4*)ee)[j];
        ushort4 o; o.x = f2bf(v.x); o.y = f2bf(v.y); o.z = f2bf(v.z); o.w = f2bf(v.w);
        ((ushort4*)eeh)[j] = o;
    }
}

// ---------------------------------------------------------------------------
// Linked-list adjacency build, NPAR parity chains per row.
// pack[e] = {next ptr, other endpoint}; writes coalesced.
// ---------------------------------------------------------------------------
__global__ __launch_bounds__(256) void build_links(
    const int* __restrict__ ui_index, const int* __restrict__ ei_index,
    int* __restrict__ head_u, int* __restrict__ head_e,
    int2* __restrict__ pack_u, int2* __restrict__ pack_e)
{
    int g = blockIdx.y;
    const int* ui = ui_index + (size_t)g * N_EDGES;
    const int* ei = ei_index + (size_t)g * N_EDGES;
    int* hu = head_u + (size_t)g * HU_STRIDE;
    int* he = head_e + (size_t)g * HE_STRIDE;
    int2* pu = pack_u + (size_t)g * N_EDGES;
    int2* pe = pack_e + (size_t)g * N_EDGES;
    int e = blockIdx.x * 256 + threadIdx.x;
    if (e >= N_EDGES) return;
    int u = ui[e], v = ei[e];
    int p = atomicExch(&hu[(u * NPAR_U) | (e & (NPAR_U - 1))], e);
    pu[e] = make_int2(p, v);
    int q = atomicExch(&he[(v * NPAR_E) | (e & (NPAR_E - 1))], e);
    pe[e] = make_int2(q, u);
}

// ---------------------------------------------------------------------------
// Lane-parallel chain walk, load-pipelined: per iteration, broadcast all NPAR
// sources, issue ALL row-gathers unconditionally (clamped index -> row 0,
// L1-resident), then masked-accumulate. No branch between loads, so the
// NPAR gathers issue back-to-back and overlap one L2 round trip.
// ---------------------------------------------------------------------------
template<int NPAR>
__device__ __forceinline__ float walkN(
    const int* __restrict__ head, const int2* __restrict__ pack,
    const ushort* __restrict__ table, int row, int lane)
{
    int e = (lane < NPAR) ? head[row * NPAR + lane] : -1;
    float s0 = 0.f, s1 = 0.f;
    while (__any(e >= 0)) {
        bool act = e >= 0;
        int2 p = pack[act ? e : 0];
        int srcb = act ? p.y : -1;
        int sc[NPAR];
        #pragma unroll
        for (int c = 0; c < NPAR; ++c) sc[c] = __shfl(srcb, c);
        float v[NPAR];
        #pragma unroll
        for (int c = 0; c < NPAR; ++c) {
            int idx = sc[c] >= 0 ? sc[c] : 0;
            v[c] = bf2f(table[(idx << 6) + lane]);
        }
        #pragma unroll
        for (int c = 0; c < NPAR; ++c) {
            float add = sc[c] >= 0 ? v[c] : 0.f;
            if (c & 1) s1 += add; else s0 += add;
        }
        e = act ? p.x : e;
    }
    return s0 + s1;
}

__device__ __forceinline__ float l2n(float v) {
    float ss = v * v;
    #pragma unroll
    for (int off = 1; off < 64; off <<= 1) ss += __shfl_xor(ss, off);
    return v / fmaxf(sqrtf(ss), 1e-12f);
}

// ---------------------------------------------------------------------------
// hop0: blocks [0, 8000) entity side (ebufh = bf16 norm(sum ueh));
//       blocks [8000, 10000) user side (acc[g] = norm(sum eeh)).
// ---------------------------------------------------------------------------
__global__ __launch_bounds__(256) void agg_hop0(
    const int* __restrict__ head_u, const int* __restrict__ head_e,
    const int2* __restrict__ pack_u, const int2* __restrict__ pack_e,
    const ushort* __restrict__ ueh, const ushort* __restrict__ eeh,
    ushort* __restrict__ ebufh, float* __restrict__ acc, int gbase)
{
    int gz = blockIdx.z;
    int g = gbase + gz;
    int w = threadIdx.x >> 6, lane = threadIdx.x & 63;
    int rb = blockIdx.x;
    if (rb < N_ENTITIES / 4) {
        int row = rb * 4 + w;
        float v = walkN<NPAR_E>(head_e + (size_t)g * HE_STRIDE,
                                pack_e + (size_t)g * N_EDGES, ueh, row, lane);
        ebufh[(size_t)gz * N_ENTITIES * EMB + (row << 6) + lane] = f2bf(l2n(v));
    } else {
        int row = (rb - N_ENTITIES / 4) * 4 + w;
        float v = walkN<NPAR_U>(head_u + (size_t)g * HU_STRIDE,
                                pack_u + (size_t)g * N_EDGES, eeh, row, lane);
        acc[(size_t)g * N_USERS * EMB + (row << 6) + lane] = l2n(v);
    }
}

// ---------------------------------------------------------------------------
// hop1 user side: acc[g] += norm(sum ebufh[gz][ei])
// ---------------------------------------------------------------------------
__global__ __launch_bounds__(256) void agg_hop1(
    const int* __restrict__ head_u, const int2* __restrict__ pack_u,
    const ushort* __restrict__ ebufh, float* __restrict__ acc, int gbase)
{
    int gz = blockIdx.z;
    int g = gbase + gz;
    int row = blockIdx.x * 4 + (threadIdx.x >> 6);
    int lane = threadIdx.x & 63;
    float v = walkN<NPAR_U>(head_u + (size_t)g * HU_STRIDE,
                            pack_u + (size_t)g * N_EDGES,
                            ebufh + (size_t)gz * N_ENTITIES * EMB, row, lane);
    acc[(size_t)g * N_USERS * EMB + (row << 6) + lane] += l2n(v);
}

// ---------------------------------------------------------------------------
// Fused: attention-combine -> out_user; proj+normalize of (uie, out_user)
// -> bf16 p1h/p2h; diag = 2*dot(n0,n1).
// ---------------------------------------------------------------------------
__global__ __launch_bounds__(256) void combine_proj(
    const float* __restrict__ acc, const float* __restrict__ uie,
    const float* __restrict__ uemb,
    const float* __restrict__ W1, const float* __restrict__ b1,
    const float* __restrict__ W2, const float* __restrict__ b2,
    float* __restrict__ out_user,
    ushort* __restrict__ p1h, ushort* __restrict__ p2h,
    float* __restrict__ diag)
{
    __shared__ float W1s[EMB * EMB];
    __shared__ float W2s[EMB * EMB];
    __shared__ float zs[4][2][EMB];
    __shared__ float hs[4][2][EMB];
    int t = threadIdx.x;
    for (int i = t; i < EMB * EMB; i += 256) { W1s[i] = W1[i]; W2s[i] = W2[i]; }
    int w = t >> 6, lane = t & 63;
    int u = blockIdx.x * 4 + w;

    float ue = uie[(u << 6) + lane];
    float av[N_GROUPS], s[N_GROUPS];
    #pragma unroll
    for (int g = 0; g < N_GROUPS; ++g) {
        av[g] = acc[(size_t)g * N_USERS * EMB + (u << 6) + lane];
        float p = av[g] * ue;
        #pragma unroll
        for (int off = 1; off < 64; off <<= 1) p += __shfl_xor(p, off);
        s[g] = p;
    }
    float m = fmaxf(fmaxf(s[0], s[1]), fmaxf(s[2], s[3]));
    float att[N_GROUPS], tot = 0.f;
    #pragma unroll
    for (int g = 0; g < N_GROUPS; ++g) { att[g] = __expf(s[g] - m); tot += att[g]; }
    float inv = 1.0f / tot;
    float o = uemb[(u << 6) + lane];
    #pragma unroll
    for (int g = 0; g < N_GROUPS; ++g) o += att[g] * inv * av[g];
    out_user[(u << 6) + lane] = o;

    zs[w][0][lane] = ue;
    zs[w][1][lane] = o;
    __syncthreads();
    float h0 = b1[lane], h1 = b1[lane];
    #pragma unroll
    for (int k = 0; k < EMB; ++k) {
        float w1 = W1s[k * EMB + lane];
        h0 = fmaf(zs[w][0][k], w1, h0);
        h1 = fmaf(zs[w][1][k], w1, h1);
    }
    h0 = h0 > 0.f ? h0 : expm1f(h0);
    h1 = h1 > 0.f ? h1 : expm1f(h1);
    hs[w][0][lane] = h0;
    hs[w][1][lane] = h1;
    __syncthreads();
    float y0 = b2[lane], y1 = b2[lane];
    #pragma unroll
    for (int k = 0; k < EMB; ++k) {
        float w2 = W2s[k * EMB + lane];
        y0 = fmaf(hs[w][0][k], w2, y0);
        y1 = fmaf(hs[w][1][k], w2, y1);
    }
    float ss0 = y0 * y0, ss1 = y1 * y1;
    #pragma unroll
    for (int off = 1; off < 64; off <<= 1) {
        ss0 += __shfl_xor(ss0, off);
        ss1 += __shfl_xor(ss1, off);
    }
    float n0 = y0 / fmaxf(sqrtf(ss0), 1e-12f);
    float n1 = y1 / fmaxf(sqrtf(ss1), 1e-12f);
    p1h[(u << 6) + lane] = f2bf(n0);
    p2h[(u << 6) + lane] = f2bf(n1);
    float d = n0 * n1;
    #pragma unroll
    for (int off = 1; off < 64; off <<= 1) d += __shfl_xor(d, off);
    if (lane == 0) diag[u] = d * 2.0f;
}

// ---------------------------------------------------------------------------
// MFMA LSE: one traversal of logits = 2 * A@B^T -> row & col exp-sum partials.
// ---------------------------------------------------------------------------
#define NCHUNK 25
#define TILES_PER_CHUNK 10
#define NWAVES (250 * NCHUNK)
__global__ __launch_bounds__(256) void lse_mfma(
    const ushort* __restrict__ Ah, const ushort* __restrict__ Bh,
    float* __restrict__ rowp, float* __restrict__ colp)
{
    int W = blockIdx.x * 4 + (threadIdx.x >> 6);
    if (W >= NWAVES) return;
    int lane = threadIdx.x & 63;
    int strip = W / NCHUNK;
    int chunk = W % NCHUNK;
    int i0 = strip * 32;
    int hl = lane >> 5;
    int l31 = lane & 31;

    const bf16x8* A8 = (const bf16x8*)Ah;
    const bf16x8* B8 = (const bf16x8*)Bh;

    bf16x8 afrag[4];
    #pragma unroll
    for (int m = 0; m < 4; ++m)
        afrag[m] = A8[(i0 + l31) * 8 + m * 2 + hl];

    float rowacc[16];
    #pragma unroll
    for (int r = 0; r < 16; ++r) rowacc[r] = 0.f;

    for (int tj = 0; tj < TILES_PER_CHUNK; ++tj) {
        int j0 = chunk * (TILES_PER_CHUNK * 32) + tj * 32;
        bf16x8 bfrag[4];
        #pragma unroll
        for (int m = 0; m < 4; ++m)
            bfrag[m] = B8[(j0 + l31) * 8 + m * 2 + hl];
        f32x16 acc;
        #pragma unroll
        for (int r = 0; r < 16; ++r) acc[r] = 0.f;
        #pragma unroll
        for (int m = 0; m < 4; ++m)
            acc = __builtin_amdgcn_mfma_f32_32x32x16_bf16(afrag[m], bfrag[m], acc, 0, 0, 0);
        float csum = 0.f;
        #pragma unroll
        for (int r = 0; r < 16; ++r) {
            float e = __expf(acc[r] * 2.0f);
            rowacc[r] += e;
            csum += e;
        }
        csum += __shfl_xor(csum, 32);
        if (lane < 32) colp[strip * 8000 + j0 + lane] = csum;
    }
    #pragma unroll
    for (int r = 0; r < 16; ++r) {
        float v = rowacc[r];
        #pragma unroll
        for (int off = 1; off < 32; off <<= 1) v += __shfl_xor(v, off);
        if (l31 == 0)
            rowp[chunk * 8000 + i0 + (r & 3) + 8 * (r >> 2) + 4 * hl] = v;
    }
}

// ---------------------------------------------------------------------------
// se_row[i] = sum_c rowp[c][i]; se_col[j] = sum_s colp[s][j]
// ---------------------------------------------------------------------------
__global__ __launch_bounds__(256) void reduce_partials(
    const float* __restrict__ rowp, const float* __restrict__ colp,
    float* __restrict__ se_row, float* __restrict__ se_col)
{
    int id = blockIdx.x * 256 + threadIdx.x;
    if (id < N_USERS) {
        float s = 0.f;
        for (int c = 0; c < NCHUNK; ++c) s += rowp[c * 8000 + id];
        se_row[id] = s;
    } else if (id < 2 * N_USERS) {
        int j = id - N_USERS;
        float s = 0.f;
        for (int st = 0; st < 250; ++st) s += colp[st * 8000 + j];
        se_col[j] = s;
    }
}

// ---------------------------------------------------------------------------
// loss = mean_i( 0.5*(log(se_row)+log(se_col)) - diag )
// ---------------------------------------------------------------------------
__global__ __launch_bounds__(256) void loss_kernel(
    const float* __restrict__ se_row, const float* __restrict__ se_col,
    const float* __restrict__ diag, float* __restrict__ out)
{
    __shared__ float red[256];
    int t = threadIdx.x;
    float s = 0.f;
    for (int i = t; i < N_USERS; i += 256)
        s += 0.5f * (logf(se_row[i]) + logf(se_col[i])) - diag[i];
    red[t] = s;
    __syncthreads();
    for (int w = 128; w > 0; w >>= 1) {
        if (t < w) red[t] += red[t + w];
        __syncthreads();
    }
    if (t == 0) out[0] = red[0] / (float)N_USERS;
}

extern "C" void kernel_launch(void* const* d_in, const int* in_sizes, int n_in,
                              void* d_out, int out_size, void* d_ws, size_t ws_size,
                              hipStream_t stream)
{
    const float* user_emb   = (const float*)d_in[0];
    const float* user_ui    = (const float*)d_in[1];
    const float* entity_emb = (const float*)d_in[2];
    const float* W1 = (const float*)d_in[3];
    const float* b1 = (const float*)d_in[4];
    const float* W2 = (const float*)d_in[5];
    const float* b2 = (const float*)d_in[6];
    const int* ui_index = (const int*)d_in[7];
    const int* ei_index = (const int*)d_in[8];

    float* ws = (float*)d_ws;
    // Layout (float units). Lifetimes stream-ordered; overlays noted.
    float* acc    = ws;                        // [0, 2,048,000) dead after combine_proj
    float* colp   = acc;                       //   overlay: lse col partials (2,000,000)
    float* se_row = ws + 2048000;              // 8,000
    float* se_col = se_row + 8000;             // 8,000
    float* diag   = se_col + 8000;             // 8,000  (ends 2,072,000)
    int* head_u = (int*)(ws + 2072000);        // 4*128,000 = 512,000 ints
    int* head_e = head_u + 4 * HU_STRIDE;      // 4*256,000 = 1,024,000 ints (ends 3,608,000)
    int2* pack_u = (int2*)(ws + 3608000);      // 4*200,000 int2 (1,600,000 f) dead after hop1
    float* rowp = (float*)pack_u;              //   overlay: lse row partials (200,000)
    int2* pack_e = pack_u + 4 * N_EDGES;       // 4*200,000 int2 (ends 6,808,000) dead after hop0
    ushort* p1h = (ushort*)pack_e;             //   overlay: 512,000 ushort
    ushort* p2h = p1h + 512000;                //   512,000 ushort (512,000 f <= 1,600,000 f)
    ushort* ueh = (ushort*)(ws + 6808000);     // 512,000 ushort (256,000 f)
    ushort* eeh = (ushort*)(ws + 7064000);     // 2,048,000 ushort (1,024,000 f; ends 8,088,000)
    ushort* ebufh = (ushort*)(ws + 8088000);   // nG * 2,048,000 ushort

    const size_t BASE_F = 8088000;
    int nG = 1;
    if (ws_size >= (BASE_F + 4 * 1024000) * 4) nG = 4;       // 48.7 MB
    else if (ws_size >= (BASE_F + 2 * 1024000) * 4) nG = 2;  // 40.5 MB

    float* out_user = (float*)d_out;           // 512,000
    float* out_loss = out_user + 512000;       // 1

    dim3 b256(256);

    hipMemsetAsync(head_u, 0xFF,
                   (size_t)(4 * HU_STRIDE + 4 * HE_STRIDE) * 4, stream);
    convert_tables<<<2500, b256, 0, stream>>>(user_emb, entity_emb, ueh, eeh);
    build_links<<<dim3((N_EDGES + 255) / 256, N_GROUPS), b256, 0, stream>>>(
        ui_index, ei_index, head_u, head_e, pack_u, pack_e);

    for (int gbase = 0; gbase < N_GROUPS; gbase += nG) {
        agg_hop0<<<dim3(N_ENTITIES / 4 + N_USERS / 4, 1, nG), b256, 0, stream>>>(
            head_u, head_e, pack_u, pack_e, ueh, eeh, ebufh, acc, gbase);
        agg_hop1<<<dim3(N_USERS / 4, 1, nG), b256, 0, stream>>>(
            head_u, pack_u, ebufh, acc, gbase);
    }

    combine_proj<<<N_USERS / 4, b256, 0, stream>>>(
        acc, user_ui, user_emb, W1, b1, W2, b2,
        out_user, p1h, p2h, diag);

    lse_mfma<<<(NWAVES + 3) / 4, b256, 0, stream>>>(p1h, p2h, rowp, colp);
    reduce_partials<<<(2 * N_USERS + 255) / 256, b256, 0, stream>>>(
        rowp, colp, se_row, se_col);
    loss_kernel<<<1, b256, 0, stream>>>(se_row, se_col, diag, out_loss);
}

// Round 8
// 267.796 us; speedup vs baseline: 5.6477x; 1.1435x over previous
//
#include <hip/hip_runtime.h>
#include <hip/hip_bf16.h>
#include <math.h>

#define N_USERS 8000
#define N_ENTITIES 32000
#define EMB 64
#define N_GROUPS 4
#define N_EDGES 200000

#define NPAR_U 16                      // parity chains per user row
#define NPAR_E 8                       // parity chains per entity row
#define HU_STRIDE (N_USERS * NPAR_U)   // 128,000 ints per group
#define HE_STRIDE (N_ENTITIES * NPAR_E)// 256,000 ints per group

typedef __attribute__((ext_vector_type(8))) __bf16 bf16x8;
typedef __attribute__((ext_vector_type(16))) float f32x16;

static __device__ __forceinline__ float bf2f(unsigned short u) {
    union { unsigned int i; float f; } x; x.i = ((unsigned int)u) << 16; return x.f;
}
static __device__ __forceinline__ unsigned short f2bf(float f) {
    union { float f; unsigned int i; } x; x.f = f;
    return (unsigned short)((x.i + 0x7FFF + ((x.i >> 16) & 1)) >> 16);
}
static __device__ __forceinline__ float u2f(unsigned int u) {
    union { unsigned int i; float f; } x; x.i = u; return x.f;
}

// ---------------------------------------------------------------------------
// Convert user_emb / entity_emb to bf16 tables.
// ---------------------------------------------------------------------------
__global__ __launch_bounds__(256) void convert_tables(
    const float* __restrict__ ue, const float* __restrict__ ee,
    ushort* __restrict__ ueh, ushort* __restrict__ eeh)
{
    int i4 = blockIdx.x * 256 + threadIdx.x;   // float4 units
    if (i4 < 128000) {
        float4 v = ((const float4*)ue)[i4];
        ushort4 o; o.x = f2bf(v.x); o.y = f2bf(v.y); o.z = f2bf(v.z); o.w = f2bf(v.w);
        ((ushort4*)ueh)[i4] = o;
    } else if (i4 < 640000) {
        int j = i4 - 128000;
        float4 v = ((const float4*)ee)[j];
        ushort4 o; o.x = f2bf(v.x); o.y = f2bf(v.y); o.z = f2bf(v.z); o.w = f2bf(v.w);
        ((ushort4*)eeh)[j] = o;
    }
}

// ---------------------------------------------------------------------------
// Linked-list adjacency build, NPAR parity chains per row.
// pack[e] = {next ptr, other endpoint}; writes coalesced.
// ---------------------------------------------------------------------------
__global__ __launch_bounds__(256) void build_links(
    const int* __restrict__ ui_index, const int* __restrict__ ei_index,
    int* __restrict__ head_u, int* __restrict__ head_e,
    int2* __restrict__ pack_u, int2* __restrict__ pack_e)
{
    int g = blockIdx.y;
    const int* ui = ui_index + (size_t)g * N_EDGES;
    const int* ei = ei_index + (size_t)g * N_EDGES;
    int* hu = head_u + (size_t)g * HU_STRIDE;
    int* he = head_e + (size_t)g * HE_STRIDE;
    int2* pu = pack_u + (size_t)g * N_EDGES;
    int2* pe = pack_e + (size_t)g * N_EDGES;
    int e = blockIdx.x * 256 + threadIdx.x;
    if (e >= N_EDGES) return;
    int u = ui[e], v = ei[e];
    int p = atomicExch(&hu[(u * NPAR_U) | (e & (NPAR_U - 1))], e);
    pu[e] = make_int2(p, v);
    int q = atomicExch(&he[(v * NPAR_E) | (e & (NPAR_E - 1))], e);
    pe[e] = make_int2(q, u);
}

// ---------------------------------------------------------------------------
// Quad-gather chain walk. Wave split: q = lane>>4 (row-in-quad), d16 = lane&15
// (4-dim slice). Per iteration, the NPAR chain cursors (held in lanes < NPAR)
// yield NPAR sources; processed as NPAR/4 quads. Each lane loads uint2 = 4
// bf16 dims of row src[4k+q] -> one VMEM instruction gathers 4 rows. Unpack
// is pure bit-ops; masking is 2 cndmask on raw dwords. Cross-quad reduce at
// the end via shfl_xor(16|32).
// ---------------------------------------------------------------------------
template<int NPAR, bool DUAL>
__device__ __forceinline__ void walk_quad(
    const int* __restrict__ head, const int2* __restrict__ pack,
    const ushort* __restrict__ tabA, const ushort* __restrict__ tabB,
    int row, int lane, float accA[4], float accB[4])
{
    int q = lane >> 4;
    int d16 = lane & 15;
    int e = (lane < NPAR) ? head[row * NPAR + lane] : -1;
    #pragma unroll
    for (int i = 0; i < 4; ++i) { accA[i] = 0.f; if (DUAL) accB[i] = 0.f; }
    while (__any(e >= 0)) {
        bool act = e >= 0;
        int2 p = pack[act ? e : 0];
        int srcb = act ? p.y : -1;
        #pragma unroll
        for (int k = 0; k < NPAR / 4; ++k) {
            int sc = __shfl(srcb, (k << 2) + q);
            int idx = sc >= 0 ? sc : 0;
            unsigned int off = ((unsigned)idx << 6) + (d16 << 2);
            uint2 ra = *(const uint2*)(tabA + off);
            uint2 rb;
            if (DUAL) rb = *(const uint2*)(tabB + off);
            if (sc < 0) { ra.x = 0u; ra.y = 0u; }
            accA[0] += u2f(ra.x << 16);
            accA[1] += u2f(ra.x & 0xFFFF0000u);
            accA[2] += u2f(ra.y << 16);
            accA[3] += u2f(ra.y & 0xFFFF0000u);
            if (DUAL) {
                if (sc < 0) { rb.x = 0u; rb.y = 0u; }
                accB[0] += u2f(rb.x << 16);
                accB[1] += u2f(rb.x & 0xFFFF0000u);
                accB[2] += u2f(rb.y << 16);
                accB[3] += u2f(rb.y & 0xFFFF0000u);
            }
        }
        e = act ? p.x : e;
    }
    #pragma unroll
    for (int i = 0; i < 4; ++i) {
        accA[i] += __shfl_xor(accA[i], 16);
        accA[i] += __shfl_xor(accA[i], 32);
        if (DUAL) {
            accB[i] += __shfl_xor(accB[i], 16);
            accB[i] += __shfl_xor(accB[i], 32);
        }
    }
}

// ---------------------------------------------------------------------------
// Entity hop0: ebufh[gz] = bf16( l2norm( sum_{edges} ueh[src] ) )
// ---------------------------------------------------------------------------
__global__ __launch_bounds__(256) void agg_entity(
    const int* __restrict__ head_e, const int2* __restrict__ pack_e,
    const ushort* __restrict__ ueh, ushort* __restrict__ ebufh, int gbase)
{
    int gz = blockIdx.z;
    int g = gbase + gz;
    int w = threadIdx.x >> 6, lane = threadIdx.x & 63;
    int row = blockIdx.x * 4 + w;
    float a[4], dummy[4];
    walk_quad<NPAR_E, false>(head_e + (size_t)g * HE_STRIDE,
                             pack_e + (size_t)g * N_EDGES,
                             ueh, nullptr, row, lane, a, dummy);
    float ss = a[0]*a[0] + a[1]*a[1] + a[2]*a[2] + a[3]*a[3];
    #pragma unroll
    for (int off = 1; off < 16; off <<= 1) ss += __shfl_xor(ss, off);
    float inv = 1.0f / fmaxf(sqrtf(ss), 1e-12f);
    if (lane < 16) {
        ushort4 o;
        o.x = f2bf(a[0] * inv); o.y = f2bf(a[1] * inv);
        o.z = f2bf(a[2] * inv); o.w = f2bf(a[3] * inv);
        *(ushort4*)(ebufh + (size_t)gz * N_ENTITIES * EMB + (row << 6) + (lane << 2)) = o;
    }
}

// ---------------------------------------------------------------------------
// User hop0+hop1 fused (same adjacency walked once, both tables gathered):
// acc[g] = l2norm(sum eeh[src]) + l2norm(sum ebufh[gz][src])
// ---------------------------------------------------------------------------
__global__ __launch_bounds__(256) void agg_user(
    const int* __restrict__ head_u, const int2* __restrict__ pack_u,
    const ushort* __restrict__ eeh, const ushort* __restrict__ ebufh,
    float* __restrict__ acc, int gbase)
{
    int gz = blockIdx.z;
    int g = gbase + gz;
    int w = threadIdx.x >> 6, lane = threadIdx.x & 63;
    int row = blockIdx.x * 4 + w;
    float a[4], b[4];
    walk_quad<NPAR_U, true>(head_u + (size_t)g * HU_STRIDE,
                            pack_u + (size_t)g * N_EDGES,
                            eeh, ebufh + (size_t)gz * N_ENTITIES * EMB,
                            row, lane, a, b);
    float ssA = a[0]*a[0] + a[1]*a[1] + a[2]*a[2] + a[3]*a[3];
    float ssB = b[0]*b[0] + b[1]*b[1] + b[2]*b[2] + b[3]*b[3];
    #pragma unroll
    for (int off = 1; off < 16; off <<= 1) {
        ssA += __shfl_xor(ssA, off);
        ssB += __shfl_xor(ssB, off);
    }
    float invA = 1.0f / fmaxf(sqrtf(ssA), 1e-12f);
    float invB = 1.0f / fmaxf(sqrtf(ssB), 1e-12f);
    if (lane < 16) {
        float4 o;
        o.x = a[0] * invA + b[0] * invB;
        o.y = a[1] * invA + b[1] * invB;
        o.z = a[2] * invA + b[2] * invB;
        o.w = a[3] * invA + b[3] * invB;
        *(float4*)(acc + (size_t)g * N_USERS * EMB + (row << 6) + (lane << 2)) = o;
    }
}

// ---------------------------------------------------------------------------
// Fused: attention-combine -> out_user; proj+normalize of (uie, out_user)
// -> bf16 p1h/p2h; diag = 2*dot(n0,n1).
// ---------------------------------------------------------------------------
__global__ __launch_bounds__(256) void combine_proj(
    const float* __restrict__ acc, const float* __restrict__ uie,
    const float* __restrict__ uemb,
    const float* __restrict__ W1, const float* __restrict__ b1,
    const float* __restrict__ W2, const float* __restrict__ b2,
    float* __restrict__ out_user,
    ushort* __restrict__ p1h, ushort* __restrict__ p2h,
    float* __restrict__ diag)
{
    __shared__ float W1s[EMB * EMB];
    __shared__ float W2s[EMB * EMB];
    __shared__ float zs[4][2][EMB];
    __shared__ float hs[4][2][EMB];
    int t = threadIdx.x;
    for (int i = t; i < EMB * EMB; i += 256) { W1s[i] = W1[i]; W2s[i] = W2[i]; }
    int w = t >> 6, lane = t & 63;
    int u = blockIdx.x * 4 + w;

    float ue = uie[(u << 6) + lane];
    float av[N_GROUPS], s[N_GROUPS];
    #pragma unroll
    for (int g = 0; g < N_GROUPS; ++g) {
        av[g] = acc[(size_t)g * N_USERS * EMB + (u << 6) + lane];
        float p = av[g] * ue;
        #pragma unroll
        for (int off = 1; off < 64; off <<= 1) p += __shfl_xor(p, off);
        s[g] = p;
    }
    float m = fmaxf(fmaxf(s[0], s[1]), fmaxf(s[2], s[3]));
    float att[N_GROUPS], tot = 0.f;
    #pragma unroll
    for (int g = 0; g < N_GROUPS; ++g) { att[g] = __expf(s[g] - m); tot += att[g]; }
    float inv = 1.0f / tot;
    float o = uemb[(u << 6) + lane];
    #pragma unroll
    for (int g = 0; g < N_GROUPS; ++g) o += att[g] * inv * av[g];
    out_user[(u << 6) + lane] = o;

    zs[w][0][lane] = ue;
    zs[w][1][lane] = o;
    __syncthreads();
    float h0 = b1[lane], h1 = b1[lane];
    #pragma unroll
    for (int k = 0; k < EMB; ++k) {
        float w1 = W1s[k * EMB + lane];
        h0 = fmaf(zs[w][0][k], w1, h0);
        h1 = fmaf(zs[w][1][k], w1, h1);
    }
    h0 = h0 > 0.f ? h0 : expm1f(h0);
    h1 = h1 > 0.f ? h1 : expm1f(h1);
    hs[w][0][lane] = h0;
    hs[w][1][lane] = h1;
    __syncthreads();
    float y0 = b2[lane], y1 = b2[lane];
    #pragma unroll
    for (int k = 0; k < EMB; ++k) {
        float w2 = W2s[k * EMB + lane];
        y0 = fmaf(hs[w][0][k], w2, y0);
        y1 = fmaf(hs[w][1][k], w2, y1);
    }
    float ss0 = y0 * y0, ss1 = y1 * y1;
    #pragma unroll
    for (int off = 1; off < 64; off <<= 1) {
        ss0 += __shfl_xor(ss0, off);
        ss1 += __shfl_xor(ss1, off);
    }
    float n0 = y0 / fmaxf(sqrtf(ss0), 1e-12f);
    float n1 = y1 / fmaxf(sqrtf(ss1), 1e-12f);
    p1h[(u << 6) + lane] = f2bf(n0);
    p2h[(u << 6) + lane] = f2bf(n1);
    float d = n0 * n1;
    #pragma unroll
    for (int off = 1; off < 64; off <<= 1) d += __shfl_xor(d, off);
    if (lane == 0) diag[u] = d * 2.0f;
}

// ---------------------------------------------------------------------------
// MFMA LSE: one traversal of logits = 2 * A@B^T -> row & col exp-sum partials.
// ---------------------------------------------------------------------------
#define NCHUNK 25
#define TILES_PER_CHUNK 10
#define NWAVES (250 * NCHUNK)
__global__ __launch_bounds__(256) void lse_mfma(
    const ushort* __restrict__ Ah, const ushort* __restrict__ Bh,
    float* __restrict__ rowp, float* __restrict__ colp)
{
    int W = blockIdx.x * 4 + (threadIdx.x >> 6);
    if (W >= NWAVES) return;
    int lane = threadIdx.x & 63;
    int strip = W / NCHUNK;
    int chunk = W % NCHUNK;
    int i0 = strip * 32;
    int hl = lane >> 5;
    int l31 = lane & 31;

    const bf16x8* A8 = (const bf16x8*)Ah;
    const bf16x8* B8 = (const bf16x8*)Bh;

    bf16x8 afrag[4];
    #pragma unroll
    for (int m = 0; m < 4; ++m)
        afrag[m] = A8[(i0 + l31) * 8 + m * 2 + hl];

    float rowacc[16];
    #pragma unroll
    for (int r = 0; r < 16; ++r) rowacc[r] = 0.f;

    for (int tj = 0; tj < TILES_PER_CHUNK; ++tj) {
        int j0 = chunk * (TILES_PER_CHUNK * 32) + tj * 32;
        bf16x8 bfrag[4];
        #pragma unroll
        for (int m = 0; m < 4; ++m)
            bfrag[m] = B8[(j0 + l31) * 8 + m * 2 + hl];
        f32x16 acc;
        #pragma unroll
        for (int r = 0; r < 16; ++r) acc[r] = 0.f;
        #pragma unroll
        for (int m = 0; m < 4; ++m)
            acc = __builtin_amdgcn_mfma_f32_32x32x16_bf16(afrag[m], bfrag[m], acc, 0, 0, 0);
        float csum = 0.f;
        #pragma unroll
        for (int r = 0; r < 16; ++r) {
            float e = __expf(acc[r] * 2.0f);
            rowacc[r] += e;
            csum += e;
        }
        csum += __shfl_xor(csum, 32);
        if (lane < 32) colp[strip * 8000 + j0 + lane] = csum;
    }
    #pragma unroll
    for (int r = 0; r < 16; ++r) {
        float v = rowacc[r];
        #pragma unroll
        for (int off = 1; off < 32; off <<= 1) v += __shfl_xor(v, off);
        if (l31 == 0)
            rowp[chunk * 8000 + i0 + (r & 3) + 8 * (r >> 2) + 4 * hl] = v;
    }
}

// ---------------------------------------------------------------------------
// se_row[i] = sum_c rowp[c][i]; se_col[j] = sum_s colp[s][j]
// ---------------------------------------------------------------------------
__global__ __launch_bounds__(256) void reduce_partials(
    const float* __restrict__ rowp, const float* __restrict__ colp,
    float* __restrict__ se_row, float* __restrict__ se_col)
{
    int id = blockIdx.x * 256 + threadIdx.x;
    if (id < N_USERS) {
        float s = 0.f;
        for (int c = 0; c < NCHUNK; ++c) s += rowp[c * 8000 + id];
        se_row[id] = s;
    } else if (id < 2 * N_USERS) {
        int j = id - N_USERS;
        float s = 0.f;
        for (int st = 0; st < 250; ++st) s += colp[st * 8000 + j];
        se_col[j] = s;
    }
}

// ---------------------------------------------------------------------------
// loss = mean_i( 0.5*(log(se_row)+log(se_col)) - diag )
// ---------------------------------------------------------------------------
__global__ __launch_bounds__(256) void loss_kernel(
    const float* __restrict__ se_row, const float* __restrict__ se_col,
    const float* __restrict__ diag, float* __restrict__ out)
{
    __shared__ float red[256];
    int t = threadIdx.x;
    float s = 0.f;
    for (int i = t; i < N_USERS; i += 256)
        s += 0.5f * (logf(se_row[i]) + logf(se_col[i])) - diag[i];
    red[t] = s;
    __syncthreads();
    for (int w = 128; w > 0; w >>= 1) {
        if (t < w) red[t] += red[t + w];
        __syncthreads();
    }
    if (t == 0) out[0] = red[0] / (float)N_USERS;
}

extern "C" void kernel_launch(void* const* d_in, const int* in_sizes, int n_in,
                              void* d_out, int out_size, void* d_ws, size_t ws_size,
                              hipStream_t stream)
{
    const float* user_emb   = (const float*)d_in[0];
    const float* user_ui    = (const float*)d_in[1];
    const float* entity_emb = (const float*)d_in[2];
    const float* W1 = (const float*)d_in[3];
    const float* b1 = (const float*)d_in[4];
    const float* W2 = (const float*)d_in[5];
    const float* b2 = (const float*)d_in[6];
    const int* ui_index = (const int*)d_in[7];
    const int* ei_index = (const int*)d_in[8];

    float* ws = (float*)d_ws;
    // Layout (float units). Lifetimes stream-ordered; overlays noted.
    float* acc    = ws;                        // [0, 2,048,000) dead after combine_proj
    float* colp   = acc;                       //   overlay: lse col partials (2,000,000)
    float* se_row = ws + 2048000;              // 8,000
    float* se_col = se_row + 8000;             // 8,000
    float* diag   = se_col + 8000;             // 8,000  (ends 2,072,000)
    int* head_u = (int*)(ws + 2072000);        // 4*128,000 = 512,000 ints
    int* head_e = head_u + 4 * HU_STRIDE;      // 4*256,000 = 1,024,000 ints (ends 3,608,000)
    int2* pack_u = (int2*)(ws + 3608000);      // 4*200,000 int2 (1,600,000 f) dead after agg_user
    float* rowp = (float*)pack_u;              //   overlay: lse row partials (200,000)
    int2* pack_e = pack_u + 4 * N_EDGES;       // 4*200,000 int2 (ends 6,808,000) dead after agg_entity
    ushort* p1h = (ushort*)pack_e;             //   overlay: 512,000 ushort
    ushort* p2h = p1h + 512000;                //   512,000 ushort (512,000 f <= 1,600,000 f)
    ushort* ueh = (ushort*)(ws + 6808000);     // 512,000 ushort (256,000 f)
    ushort* eeh = (ushort*)(ws + 7064000);     // 2,048,000 ushort (1,024,000 f; ends 8,088,000)
    ushort* ebufh = (ushort*)(ws + 8088000);   // nG * 2,048,000 ushort

    const size_t BASE_F = 8088000;
    int nG = 1;
    if (ws_size >= (BASE_F + 4 * 1024000) * 4) nG = 4;       // 48.7 MB
    else if (ws_size >= (BASE_F + 2 * 1024000) * 4) nG = 2;  // 40.5 MB

    float* out_user = (float*)d_out;           // 512,000
    float* out_loss = out_user + 512000;       // 1

    dim3 b256(256);

    hipMemsetAsync(head_u, 0xFF,
                   (size_t)(4 * HU_STRIDE + 4 * HE_STRIDE) * 4, stream);
    convert_tables<<<2500, b256, 0, stream>>>(user_emb, entity_emb, ueh, eeh);
    build_links<<<dim3((N_EDGES + 255) / 256, N_GROUPS), b256, 0, stream>>>(
        ui_index, ei_index, head_u, head_e, pack_u, pack_e);

    for (int gbase = 0; gbase < N_GROUPS; gbase += nG) {
        agg_entity<<<dim3(N_ENTITIES / 4, 1, nG), b256, 0, stream>>>(
            head_e, pack_e, ueh, ebufh, gbase);
        agg_user<<<dim3(N_USERS / 4, 1, nG), b256, 0, stream>>>(
            head_u, pack_u, eeh, ebufh, acc, gbase);
    }

    combine_proj<<<N_USERS / 4, b256, 0, stream>>>(
        acc, user_ui, user_emb, W1, b1, W2, b2,
        out_user, p1h, p2h, diag);

    lse_mfma<<<(NWAVES + 3) / 4, b256, 0, stream>>>(p1h, p2h, rowp, colp);
    reduce_partials<<<(2 * N_USERS + 255) / 256, b256, 0, stream>>>(
        rowp, colp, se_row, se_col);
    loss_kernel<<<1, b256, 0, stream>>>(se_row, se_col, diag, out_loss);
}